// Round 15
// baseline (275.631 us; speedup 1.0000x reference)
//
#include <hip/hip_runtime.h>

#define NPTS 65536

typedef __bf16 bf16_t;
typedef __bf16 bf16x8 __attribute__((ext_vector_type(8)));
typedef float f32x16 __attribute__((ext_vector_type(16)));

#define MFMA32(A, B, C) __builtin_amdgcn_mfma_f32_32x32x16_bf16(A, B, C, 0, 0, 0)

__device__ __forceinline__ float relu(float v) { return v > 0.f ? v : 0.f; }

// ======================================================================
// Layouts (128-pt blocks, 4 mi slots):
// Activation (C ch): octet idx = ((b*(C/16)+kc)*4+mi)*64 + l
//   point = b*128 + mi*32 + (l&31); channel = kc*16 + (l>>5)*8 + j
// Weight (N x K): octet idx = (st*(K/16)+kc)*64 + l; n = st*32+(l&31); k = kc*16+(l>>5)*8+j
// ======================================================================

struct PrepSeg { const float* src; bf16_t* h; bf16_t* l; int SW; int K; int nblk; };
struct PrepAll { PrepSeg seg[6]; };

__global__ __launch_bounds__(256) void kprep(PrepAll pa) {
  int blk = blockIdx.x, i = 0;
  while (blk >= pa.seg[i].nblk) { blk -= pa.seg[i].nblk; ++i; }
  const PrepSeg sg = pa.seg[i];
  int t8 = blk * 256 + threadIdx.x;
  int l = t8 & 63;
  int rest = t8 >> 6;
  int NKC = sg.K >> 4;
  int kc = rest % NKC, st = rest / NKC;
  int n = st * 32 + (l & 31);
  int k0 = kc * 16 + (l >> 5) * 8;
  const float* src = sg.src + (size_t)n * sg.SW + k0;
  bf16x8 hv, lv;
#pragma unroll
  for (int j = 0; j < 8; ++j) {
    float v = src[j];
    bf16_t h = (bf16_t)v;
    hv[j] = h; lv[j] = (bf16_t)(v - (float)h);
  }
  *(bf16x8*)(sg.h + (size_t)t8 * 8) = hv;
  *(bf16x8*)(sg.l + (size_t)t8 * 8) = lv;
}

// ============ k1a: h1 = relu(x@W1.T+b1) in activation order
__global__ __launch_bounds__(256, 2) void k1a(
    const float* __restrict__ x, const float* __restrict__ W1, const float* __restrict__ b1,
    bf16_t* __restrict__ h1h, bf16_t* __restrict__ h1l) {
  int p = blockIdx.x * 256 + threadIdx.x;
  float x0 = x[p * 3 + 0], x1 = x[p * 3 + 1], x2 = x[p * 3 + 2];
  int b = p >> 7, mi = (p >> 5) & 3, p31 = p & 31;
#pragma unroll
  for (int kc = 0; kc < 4; ++kc)
#pragma unroll
    for (int hbw = 0; hbw < 2; ++hbw) {
      bf16x8 hv, lv;
#pragma unroll
      for (int j = 0; j < 8; ++j) {
        int c = kc * 16 + hbw * 8 + j;
        float v = relu(fmaf(W1[c * 3], x0, fmaf(W1[c * 3 + 1], x1, fmaf(W1[c * 3 + 2], x2, b1[c]))));
        bf16_t h = (bf16_t)v;
        hv[j] = h; lv[j] = (bf16_t)(v - (float)h);
      }
      size_t off = (((size_t)(b * 4 + kc) * 4 + mi) * 64 + hbw * 32 + p31) * 8;
      *(bf16x8*)(h1h + off) = hv;
      *(bf16x8*)(h1l + off) = lv;
    }
}

// ============ shared epilogue helpers
struct Oct { bf16x8 h0, l0, h1, l1; };
__device__ __forceinline__ Oct epi_pack(const f32x16& accv, int hb) {
  float a[16], rcv[8];
#pragma unroll
  for (int r = 0; r < 16; ++r) a[r] = relu(accv[r]);
#pragma unroll
  for (int j = 0; j < 8; ++j) rcv[j] = __shfl_xor(hb ? a[j] : a[8 + j], 32);
  float o0[8], o1[8];
#pragma unroll
  for (int j = 0; j < 4; ++j) {
    o0[j]     = hb ? rcv[j]     : a[j];
    o0[4 + j] = hb ? a[8 + j]   : rcv[j];
    o1[j]     = hb ? rcv[4 + j] : a[4 + j];
    o1[4 + j] = hb ? a[12 + j]  : rcv[4 + j];
  }
  Oct o;
#pragma unroll
  for (int j = 0; j < 8; ++j) {
    bf16_t x0 = (bf16_t)o0[j]; o.h0[j] = x0; o.l0[j] = (bf16_t)(o0[j] - (float)x0);
    bf16_t x1 = (bf16_t)o1[j]; o.h1[j] = x1; o.l1[j] = (bf16_t)(o1[j] - (float)x1);
  }
  return o;
}

__device__ __forceinline__ void epi_store_lds(const Oct& o, bf16_t* H, bf16_t* L, int ob, int p31) {
  *(bf16x8*)(H + (ob + p31) * 8)      = o.h0;
  *(bf16x8*)(H + (ob + 32 + p31) * 8) = o.h1;
  *(bf16x8*)(L + (ob + p31) * 8)      = o.l0;
  *(bf16x8*)(L + (ob + 32 + p31) * 8) = o.l1;
}

__device__ __forceinline__ void binit2(f32x16 acc[2], const float* bias, int base, int hb) {
#pragma unroll
  for (int r = 0; r < 16; ++r) {
    float bv = bias[base + 8 * (r >> 2) + 4 * hb + (r & 3)];
    acc[0][r] = bv; acc[1][r] = bv;
  }
}

// ============ gemmS: D = W·X^T, 3-term split 32x32x16 bf16 MFMA (L2 only)
template <int PB, int K, int MODE>
__global__ __launch_bounds__(256, 3) void gemmS(
    const bf16_t* __restrict__ Ah, const bf16_t* __restrict__ Al,
    const bf16_t* __restrict__ Wh, const bf16_t* __restrict__ Wl,
    const float* __restrict__ bias, int nko,
    bf16_t* __restrict__ Oh, bf16_t* __restrict__ Ol,
    float* __restrict__ aux, const float* __restrict__ w8, const float* __restrict__ b8) {
  constexpr int WC = 4 / PB;
  constexpr int NKC = K / 16;
  constexpr int KG = 2;
  constexpr int NG = NKC / KG;
  __shared__ bf16_t smem[2][PB][2][KG * 2048];

  int tid = threadIdx.x;
  int lane = tid & 63;
  int w = __builtin_amdgcn_readfirstlane(tid >> 6);
  int rg = w / WC, cw = w % WC;
  int hb = lane >> 5, p31 = lane & 31;
  int bx = blockIdx.x;
  int st0 = blockIdx.y * WC + cw;
  int bblk = bx * PB + rg;

  f32x16 acc[4];
#pragma unroll
  for (int r = 0; r < 16; ++r) {
    float bv = bias[st0 * 32 + 8 * (r >> 2) + 4 * hb + (r & 3)];
#pragma unroll
    for (int mi = 0; mi < 4; ++mi) acc[mi][r] = bv;
  }

  auto stage = [&](int buf, int g) {
#pragma unroll
    for (int i = 0; i < PB * 4; ++i) {
      int u = i * 256 + tid;
      int rgs = u >> 10, rem = u & 1023;
      int t = rem >> 9, inner = rem & 511;
      const bf16_t* src = (t ? Al : Ah) +
          ((size_t)(bx * PB + rgs) * NKC + g * KG) * 2048 + inner * 8;
      *(bf16x8*)&smem[buf][rgs][t][inner * 8] = *(const bf16x8*)src;
    }
  };

  bf16x8 wch[KG], wcl[KG], wnh[KG], wnl[KG];
  auto wload = [&](int g, bf16x8* h, bf16x8* l) {
#pragma unroll
    for (int kcl = 0; kcl < KG; ++kcl) {
      size_t wo = (((size_t)st0 * NKC + g * KG + kcl) * 64 + lane) * 8;
      h[kcl] = *(const bf16x8*)(Wh + wo);
      l[kcl] = *(const bf16x8*)(Wl + wo);
    }
  };

  auto compute = [&](int buf, bf16x8* h, bf16x8* l) {
#pragma unroll
    for (int kcl = 0; kcl < KG; ++kcl)
#pragma unroll
      for (int mi = 0; mi < 4; ++mi) {
        const bf16_t* xp = &smem[buf][rg][0][((kcl * 4 + mi) * 64 + lane) * 8];
        bf16x8 xh = *(const bf16x8*)xp;
        bf16x8 xl = *(const bf16x8*)(xp + KG * 2048);
        acc[mi] = MFMA32(h[kcl], xh, acc[mi]);
        acc[mi] = MFMA32(l[kcl], xh, acc[mi]);
        acc[mi] = MFMA32(h[kcl], xl, acc[mi]);
      }
  };

  stage(0, 0);
  wload(0, wch, wcl);
  for (int g = 0; g < NG; ++g) {
    __syncthreads();
    if (g + 1 < NG) {
      stage((g + 1) & 1, g + 1);
      wload(g + 1, wnh, wnl);
    }
    compute(g & 1, wch, wcl);
#pragma unroll
    for (int kcl = 0; kcl < KG; ++kcl) { wch[kcl] = wnh[kcl]; wcl[kcl] = wnl[kcl]; }
  }

  if constexpr (MODE == 0) {
#pragma unroll
    for (int mi = 0; mi < 4; ++mi) {
      Oct o = epi_pack(acc[mi], hb);
      int kco = st0 * 2 + hb;
      size_t ob = ((size_t)(bblk * nko + kco) * 4 + mi) * 64;
      *(bf16x8*)(Oh + (ob + p31) * 8)      = o.h0;
      *(bf16x8*)(Ol + (ob + p31) * 8)      = o.l0;
      *(bf16x8*)(Oh + (ob + 32 + p31) * 8) = o.h1;
      *(bf16x8*)(Ol + (ob + 32 + p31) * 8) = o.l1;
    }
  } else if constexpr (MODE == 1) {
#pragma unroll
    for (int r = 0; r < 16; ++r) {
      float m = relu(acc[0][r]);
#pragma unroll
      for (int mi = 1; mi < 4; ++mi) m = fmaxf(m, relu(acc[mi][r]));
#pragma unroll
      for (int off = 1; off < 32; off <<= 1) m = fmaxf(m, __shfl_xor(m, off));
      if (p31 == 0)
        aux[(size_t)bx * 1024 + st0 * 32 + 8 * (r >> 2) + 4 * hb + (r & 3)] = m;
    }
  } else {
    __shared__ float sp[4][128];
    float w8v[16];
#pragma unroll
    for (int r = 0; r < 16; ++r) w8v[r] = w8[st0 * 32 + 8 * (r >> 2) + 4 * hb + (r & 3)];
#pragma unroll
    for (int mi = 0; mi < 4; ++mi) {
      float s = 0.f;
#pragma unroll
      for (int r = 0; r < 16; ++r) s = fmaf(relu(acc[mi][r]), w8v[r], s);
      s += __shfl_xor(s, 32);
      if (hb == 0) sp[w][mi * 32 + p31] = s;
    }
    __syncthreads();
    if (tid < 128)
      aux[(size_t)bx * 128 + tid] = sp[0][tid] + sp[1][tid] + sp[2][tid] + sp[3][tid] + b8[0];
  }
}

// ============ kl34max v6: FUSED L3+L4+GLOBAL-MAX. v4 structure (measured 75.9 us)
// with the final per-block channel-max going DIRECTLY to g via atomicMax
// (uint-compare exact for relu outputs >= 0; g memset to 0; max is
// order-independent -> bit-identical). Deletes gpart (2 MB write + 2 MB read)
// and the kgmax dispatch entirely.
__global__ __launch_bounds__(512, 1) void kl34max(
    const bf16_t* __restrict__ h2h, const bf16_t* __restrict__ h2l,
    const bf16_t* __restrict__ W3h, const bf16_t* __restrict__ W3l,
    const float* __restrict__ b3,
    const bf16_t* __restrict__ Wh, const bf16_t* __restrict__ Wl,
    const float* __restrict__ bias, float* __restrict__ g) {
  __shared__ __align__(16) bf16_t sA[81920];  // y3 [0,65536); wq [65536,81920)
  bf16_t* wq = sA + 65536;
  int tid = threadIdx.x, lane = tid & 63;
  int w = __builtin_amdgcn_readfirstlane(tid >> 6);   // 0..7
  int w3 = w & 3, t = w >> 2;                         // strip-slot, tile
  int hb = lane >> 5, p31 = lane & 31;
  int bx = blockIdx.x;
  int pb = bx * 2 + t;
  int rot = (bx >> 2) & 7;
  bf16_t* sT = sA + t * 32768;
  bf16_t* wbuf = wq + w * 2048;  // per-wave 4 KB: 2 buffers x (512 el h + 512 el l)

  // ---- phase 1: y3(tile t) = relu(h2@W3.T+b3) -> LDS. h2 B-frags for mi=w3.
  {
    bf16x8 hx[4], lx[4];
#pragma unroll
    for (int kc = 0; kc < 4; ++kc) {
      size_t so = (((size_t)(pb * 4 + kc) * 4 + w3) * 64 + lane) * 8;
      hx[kc] = *(const bf16x8*)(h2h + so);
      lx[kc] = *(const bf16x8*)(h2l + so);
    }
#pragma unroll
    for (int spr = 0; spr < 2; ++spr) {
      f32x16 a3[2];
#pragma unroll
      for (int s = 0; s < 2; ++s) {
        int st = spr * 2 + s;
#pragma unroll
        for (int r = 0; r < 16; ++r)
          a3[s][r] = b3[st * 32 + 8 * (r >> 2) + 4 * hb + (r & 3)];
      }
#pragma unroll
      for (int kc = 0; kc < 4; ++kc)
#pragma unroll
        for (int s = 0; s < 2; ++s) {
          int st = spr * 2 + s;
          size_t wo = ((size_t)(st * 4 + kc) * 64 + lane) * 8;
          bf16x8 wh3 = *(const bf16x8*)(W3h + wo);
          bf16x8 wl3 = *(const bf16x8*)(W3l + wo);
          a3[s] = MFMA32(wh3, hx[kc], a3[s]);
          a3[s] = MFMA32(wl3, hx[kc], a3[s]);
          a3[s] = MFMA32(wh3, lx[kc], a3[s]);
        }
#pragma unroll
      for (int s = 0; s < 2; ++s) {
        int st = spr * 2 + s;
        Oct o = epi_pack(a3[s], hb);
        epi_store_lds(o, sT, sT + 16384, ((st * 2 + hb) * 4 + w3) * 64, p31);
      }
    }
  }
  __syncthreads();  // y3 ready — the ONLY block-wide barrier

  // ---- phase 2: barrier-free per-wave weight pipeline over 64 (j,kc) phases
  auto issueW = [&](int u) {
    int jj = u >> 3, kc = u & 7;
    int st = ((jj + rot) & 7) * 4 + w3;
    const bf16_t* gph = Wh + ((size_t)(st * 8 + kc) * 64 + lane) * 8;
    const bf16_t* gpl = Wl + ((size_t)(st * 8 + kc) * 64 + lane) * 8;
    bf16_t* lp = wbuf + (u & 1) * 1024;  // wave-uniform base; DMA writes lane*16B
    __builtin_amdgcn_global_load_lds(
        (const __attribute__((address_space(1))) void*)gph,
        (__attribute__((address_space(3))) void*)lp, 16, 0, 0);
    __builtin_amdgcn_global_load_lds(
        (const __attribute__((address_space(1))) void*)gpl,
        (__attribute__((address_space(3))) void*)(lp + 512), 16, 0, 0);
  };
  issueW(0);

  f32x16 acc[4];
#pragma unroll 1
  for (int u = 0; u < 64; ++u) {
    if (u + 1 < 64) {
      issueW(u + 1);
      asm volatile("s_waitcnt vmcnt(2)" ::: "memory");  // DMA(u) landed; DMA(u+1) in flight
    } else {
      asm volatile("s_waitcnt vmcnt(0)" ::: "memory");
    }
    __builtin_amdgcn_sched_barrier(0);  // rule #18: pin reads after the wait
    int jj = u >> 3, kc = u & 7;
    int st = ((jj + rot) & 7) * 4 + w3;
    if (kc == 0) {
#pragma unroll
      for (int r = 0; r < 16; ++r) {
        float bv = bias[st * 32 + 8 * (r >> 2) + 4 * hb + (r & 3)];
#pragma unroll
        for (int mi = 0; mi < 4; ++mi) acc[mi][r] = bv;
      }
    }
    const bf16_t* wb = wbuf + (u & 1) * 1024;
    bf16x8 cwh = *(const bf16x8*)(wb + lane * 8);
    bf16x8 cwl = *(const bf16x8*)(wb + 512 + lane * 8);
    __builtin_amdgcn_s_setprio(1);
#pragma unroll
    for (int mi = 0; mi < 4; ++mi) {
      const bf16_t* xp = sT + ((kc * 4 + mi) * 64 + lane) * 8;
      bf16x8 xh = *(const bf16x8*)xp;
      bf16x8 xl = *(const bf16x8*)(xp + 16384);
      acc[mi] = MFMA32(cwh, xh, acc[mi]);
      acc[mi] = MFMA32(cwl, xh, acc[mi]);
      acc[mi] = MFMA32(cwh, xl, acc[mi]);
    }
    __builtin_amdgcn_s_setprio(0);
    if (kc == 7) {
#pragma unroll
      for (int r = 0; r < 16; ++r) {
        float m = fmaxf(fmaxf(acc[0][r], acc[1][r]), fmaxf(acc[2][r], acc[3][r]));
        m = fmaxf(m, 0.f);  // relu folded into the max
#pragma unroll
        for (int off = 1; off < 32; off <<= 1) m = fmaxf(m, __shfl_xor(m, off));
        if (p31 == 0)
          atomicMax((unsigned int*)(g + st * 32 + 8 * (r >> 2) + 4 * hb + (r & 3)),
                    __float_as_uint(m));
      }
    }
  }
}

// ============ kc5 v3: c5[c] = W5[c][64:1088] @ g + b5[c], COALESCED.
// 32 blocks x 4 waves = 128 waves x 4 channels = 512 = L5 output count.
__global__ __launch_bounds__(256) void kc5(
    const float* __restrict__ W5, const float* __restrict__ b5,
    const float* __restrict__ g, float* __restrict__ c5) {
  int lane = threadIdx.x & 63;
  int wv = blockIdx.x * 4 + (threadIdx.x >> 6);  // 128 waves
  float gv[16];
#pragma unroll
  for (int k = 0; k < 16; ++k) gv[k] = g[k * 64 + lane];
#pragma unroll
  for (int i = 0; i < 4; ++i) {
    int c = wv * 4 + i;  // 0..511
    const float* wrow = W5 + (size_t)c * 1088 + 64;
    float acc = 0.f;
#pragma unroll
    for (int k = 0; k < 16; ++k) acc = fmaf(wrow[k * 64 + lane], gv[k], acc);
#pragma unroll
    for (int off = 1; off < 64; off <<= 1) acc += __shfl_xor(acc, off);
    if (lane == 0) c5[c] = acc + b5[c];
  }
}

// ======================================================================
// mega2 v2 (R11/R14 verbatim): h2 -> z5 -> z6 -> z7 -> out, 64-pt blocks.
// ======================================================================

__global__ __launch_bounds__(256, 2) void mega2(
    const bf16_t* __restrict__ h2gh, const bf16_t* __restrict__ h2gl,
    const bf16_t* __restrict__ W5h, const bf16_t* __restrict__ W5l, const float* __restrict__ c5,
    const bf16_t* __restrict__ W6h, const bf16_t* __restrict__ W6l, const float* __restrict__ b6,
    const bf16_t* __restrict__ W7h, const bf16_t* __restrict__ W7l, const float* __restrict__ b7,
    const float* __restrict__ w8, const float* __restrict__ b8v, float* __restrict__ out) {
  __shared__ __align__(16) bf16_t smem[32768];
  __shared__ float sp[4][64];
  int tid = threadIdx.x, lane = tid & 63;
  int w = __builtin_amdgcn_readfirstlane(tid >> 6);
  int hb = lane >> 5, p31 = lane & 31;
  int b = blockIdx.x;
  int B = b >> 1, half = b & 1;

  bf16x8 xh[4][2], xl[4][2];
#pragma unroll
  for (int kc = 0; kc < 4; ++kc)
#pragma unroll
    for (int mi = 0; mi < 2; ++mi) {
      size_t so = (((size_t)((B * 4 + kc) * 4 + half * 2 + mi)) * 64 + lane) * 8;
      xh[kc][mi] = *(const bf16x8*)(h2gh + so);
      xl[kc][mi] = *(const bf16x8*)(h2gl + so);
    }

  f32x16 z6a[2][2];
#pragma unroll
  for (int s = 0; s < 2; ++s)
#pragma unroll
    for (int r = 0; r < 16; ++r) {
      float bv = b6[(w * 2 + s) * 32 + 8 * (r >> 2) + 4 * hb + (r & 3)];
      z6a[s][0][r] = bv; z6a[s][1][r] = bv;
    }

  bf16x8 w5h[4], w5l[4];
  auto w5load = [&](int g) {
#pragma unroll
    for (int kc = 0; kc < 4; ++kc) {
      size_t wo = (((size_t)(g * 4 + w) * 4 + kc) * 64 + lane) * 8;
      w5h[kc] = *(const bf16x8*)(W5h + wo);
      w5l[kc] = *(const bf16x8*)(W5l + wo);
    }
  };
  w5load(0);

  bf16x8 cwh[2], cwl[2], nwh[2], nwl[2];
  auto w6load = [&](int g, int kc, bf16x8* hh, bf16x8* ll) {
#pragma unroll
    for (int s = 0; s < 2; ++s) {
      size_t wo = ((size_t)((w * 2 + s) * 32 + g * 8 + kc) * 64 + lane) * 8;
      hh[s] = *(const bf16x8*)(W6h + wo);
      ll[s] = *(const bf16x8*)(W6l + wo);
    }
  };

  for (int g5 = 0; g5 < 4; ++g5) {
    bf16_t* zbuf = smem + (g5 & 1) * 16384;
    int st5 = g5 * 4 + w;
    f32x16 a5[2];
    binit2(a5, c5, st5 * 32, hb);
    __builtin_amdgcn_s_setprio(1);
#pragma unroll
    for (int kc = 0; kc < 4; ++kc) {
#pragma unroll
      for (int mi = 0; mi < 2; ++mi) a5[mi] = MFMA32(w5h[kc], xh[kc][mi], a5[mi]);
#pragma unroll
      for (int mi = 0; mi < 2; ++mi) a5[mi] = MFMA32(w5l[kc], xh[kc][mi], a5[mi]);
#pragma unroll
      for (int mi = 0; mi < 2; ++mi) a5[mi] = MFMA32(w5h[kc], xl[kc][mi], a5[mi]);
    }
    __builtin_amdgcn_s_setprio(0);
    if (g5 < 3) w5load(g5 + 1);
#pragma unroll
    for (int mi = 0; mi < 2; ++mi) {
      Oct o = epi_pack(a5[mi], hb);
      epi_store_lds(o, zbuf, zbuf + 8192, ((w * 2 + hb) * 2 + mi) * 64, p31);
    }
    w6load(g5, 0, cwh, cwl);
    __syncthreads();
#pragma unroll
    for (int kc = 0; kc < 8; ++kc) {
      if (kc < 7) w6load(g5, kc + 1, nwh, nwl);
      bf16x8 zxh[2], zxl[2];
#pragma unroll
      for (int mi = 0; mi < 2; ++mi) {
        const bf16_t* xp = zbuf + ((kc * 2 + mi) * 64 + lane) * 8;
        zxh[mi] = *(const bf16x8*)xp;
        zxl[mi] = *(const bf16x8*)(xp + 8192);
      }
      __builtin_amdgcn_s_setprio(1);
#pragma unroll
      for (int s = 0; s < 2; ++s)
#pragma unroll
        for (int mi = 0; mi < 2; ++mi) z6a[s][mi] = MFMA32(cwh[s], zxh[mi], z6a[s][mi]);
#pragma unroll
      for (int s = 0; s < 2; ++s)
#pragma unroll
        for (int mi = 0; mi < 2; ++mi) z6a[s][mi] = MFMA32(cwl[s], zxh[mi], z6a[s][mi]);
#pragma unroll
      for (int s = 0; s < 2; ++s)
#pragma unroll
        for (int mi = 0; mi < 2; ++mi) z6a[s][mi] = MFMA32(cwh[s], zxl[mi], z6a[s][mi]);
      __builtin_amdgcn_s_setprio(0);
#pragma unroll
      for (int s = 0; s < 2; ++s) { cwh[s] = nwh[s]; cwl[s] = nwl[s]; }
    }
  }
  __syncthreads();
#pragma unroll
  for (int s = 0; s < 2; ++s) {
    int kcb = (w * 2 + s) * 2 + hb;
#pragma unroll
    for (int mi = 0; mi < 2; ++mi) {
      Oct o = epi_pack(z6a[s][mi], hb);
      epi_store_lds(o, smem, smem + 16384, (kcb * 2 + mi) * 64, p31);
    }
  }
  bf16x8 a7wh, a7wl, n7h, n7l;
  {
    size_t wo = ((size_t)(w * 16) * 64 + lane) * 8;
    a7wh = *(const bf16x8*)(W7h + wo);
    a7wl = *(const bf16x8*)(W7l + wo);
  }
  __syncthreads();
  f32x16 a7[2];
  binit2(a7, b7, w * 32, hb);
#pragma unroll
  for (int kc = 0; kc < 16; ++kc) {
    if (kc < 15) {
      size_t wo = ((size_t)(w * 16 + kc + 1) * 64 + lane) * 8;
      n7h = *(const bf16x8*)(W7h + wo);
      n7l = *(const bf16x8*)(W7l + wo);
    }
    bf16x8 zxh[2], zxl[2];
#pragma unroll
    for (int mi = 0; mi < 2; ++mi) {
      const bf16_t* xp = smem + ((kc * 2 + mi) * 64 + lane) * 8;
      zxh[mi] = *(const bf16x8*)xp;
      zxl[mi] = *(const bf16x8*)(xp + 16384);
    }
    __builtin_amdgcn_s_setprio(1);
#pragma unroll
    for (int mi = 0; mi < 2; ++mi) a7[mi] = MFMA32(a7wh, zxh[mi], a7[mi]);
#pragma unroll
    for (int mi = 0; mi < 2; ++mi) a7[mi] = MFMA32(a7wl, zxh[mi], a7[mi]);
#pragma unroll
    for (int mi = 0; mi < 2; ++mi) a7[mi] = MFMA32(a7wh, zxl[mi], a7[mi]);
    __builtin_amdgcn_s_setprio(0);
    a7wh = n7h; a7wl = n7l;
  }
  float w8v[16];
#pragma unroll
  for (int r = 0; r < 16; ++r) w8v[r] = w8[w * 32 + 8 * (r >> 2) + 4 * hb + (r & 3)];
#pragma unroll
  for (int mi = 0; mi < 2; ++mi) {
    float s = 0.f;
#pragma unroll
    for (int r = 0; r < 16; ++r) s = fmaf(relu(a7[mi][r]), w8v[r], s);
    s += __shfl_xor(s, 32);
    if (hb == 0) sp[w][mi * 32 + p31] = s;
  }
  __syncthreads();
  if (tid < 64)
    out[b * 64 + tid] = sp[0][tid] + sp[1][tid] + sp[2][tid] + sp[3][tid] + b8v[0];
}

extern "C" void kernel_launch(void* const* d_in, const int* in_sizes, int n_in,
                              void* d_out, int out_size, void* d_ws, size_t ws_size,
                              hipStream_t stream) {
  const float* x  = (const float*)d_in[0];
  const float* W1 = (const float*)d_in[1];  const float* b1 = (const float*)d_in[2];
  const float* W2 = (const float*)d_in[3];  const float* b2 = (const float*)d_in[4];
  const float* W3 = (const float*)d_in[5];  const float* b3 = (const float*)d_in[6];
  const float* W4 = (const float*)d_in[7];  const float* b4 = (const float*)d_in[8];
  const float* W5 = (const float*)d_in[9];  const float* b5 = (const float*)d_in[10];
  const float* W6 = (const float*)d_in[11]; const float* b6 = (const float*)d_in[12];
  const float* W7 = (const float*)d_in[13]; const float* b7 = (const float*)d_in[14];
  const float* W8 = (const float*)d_in[15]; const float* b8 = (const float*)d_in[16];
  float* out = (float*)d_out;

  // Workspace overlays:
  //   h2 pair [128,136)+[136,144)  L2->kl34max,mega2
  //   h1 pair [144,152)+[152,160)  k1a->L2
  //   g/c5 [210,..), weight frags after
  const size_t MB = 1ull << 20;
  char* ws = (char*)d_ws;
  bf16_t* h2h = (bf16_t*)(ws + 128 * MB);  bf16_t* h2l = (bf16_t*)(ws + 136 * MB);
  bf16_t* h1h = (bf16_t*)(ws + 144 * MB);  bf16_t* h1l = (bf16_t*)(ws + 152 * MB);
  float* g     = (float*)(ws + 210 * MB);
  float* c5    = (float*)(ws + 210 * MB + 4096);
  char* wb = ws + 210 * MB + 65536;
  bf16_t* W2h = (bf16_t*)(wb);             bf16_t* W2l = (bf16_t*)(wb + 8192);
  bf16_t* W3h = (bf16_t*)(wb + 16384);     bf16_t* W3l = (bf16_t*)(wb + 32768);
  bf16_t* W4h = (bf16_t*)(wb + 49152);     bf16_t* W4l = (bf16_t*)(wb + 311296);
  bf16_t* W5h = (bf16_t*)(wb + 573440);    bf16_t* W5l = (bf16_t*)(wb + 638976);
  bf16_t* W6h = (bf16_t*)(wb + 704512);    bf16_t* W6l = (bf16_t*)(wb + 966656);
  bf16_t* W7h = (bf16_t*)(wb + 1228800);   bf16_t* W7l = (bf16_t*)(wb + 1294336);

  hipMemsetAsync(g, 0, 1024 * sizeof(float), stream);  // max identity (relu outputs >= 0)

  PrepAll pa;
  pa.seg[0] = {W2, W2h, W2l, 64, 64, 2};
  pa.seg[1] = {W3, W3h, W3l, 64, 64, 4};
  pa.seg[2] = {W4, W4h, W4l, 128, 128, 64};
  pa.seg[3] = {W5, W5h, W5l, 1088, 64, 16};   // W5[:, :64]
  pa.seg[4] = {W6, W6h, W6l, 512, 512, 64};
  pa.seg[5] = {W7, W7h, W7l, 256, 256, 16};
  kprep<<<166, 256, 0, stream>>>(pa);

  k1a<<<256, 256, 0, stream>>>(x, W1, b1, h1h, h1l);
  gemmS<2, 64, 0><<<dim3(256, 1), 256, 0, stream>>>(
      h1h, h1l, W2h, W2l, b2, 4, h2h, h2l, nullptr, nullptr, nullptr);        // L2
  kl34max<<<256, 512, 0, stream>>>(h2h, h2l, W3h, W3l, b3, W4h, W4l, b4, g);  // L3+L4+max
  kc5<<<32, 256, 0, stream>>>(W5, b5, g, c5);
  mega2<<<1024, 256, 0, stream>>>(h2h, h2l, W5h, W5l, c5, W6h, W6l, b6,
                                  W7h, W7l, b7, W8, b8, out);                 // L5..L8 fused
}

// Round 16
// 249.763 us; speedup vs baseline: 1.1036x; 1.1036x over previous
//
#include <hip/hip_runtime.h>

#define NPTS 65536

typedef __bf16 bf16_t;
typedef __bf16 bf16x8 __attribute__((ext_vector_type(8)));
typedef float f32x16 __attribute__((ext_vector_type(16)));

#define MFMA32(A, B, C) __builtin_amdgcn_mfma_f32_32x32x16_bf16(A, B, C, 0, 0, 0)

__device__ __forceinline__ float relu(float v) { return v > 0.f ? v : 0.f; }

// ======================================================================
// Layouts (128-pt blocks, 4 mi slots):
// Activation (C ch): octet idx = ((b*(C/16)+kc)*4+mi)*64 + l
//   point = b*128 + mi*32 + (l&31); channel = kc*16 + (l>>5)*8 + j
// Weight (N x K): octet idx = (st*(K/16)+kc)*64 + l; n = st*32+(l&31); k = kc*16+(l>>5)*8+j
// ======================================================================

struct PrepSeg { const float* src; bf16_t* h; bf16_t* l; int SW; int K; int nblk; };
struct PrepAll { PrepSeg seg[6]; };

// ============ kprep_k1a: FUSED independent front-end work (one dispatch).
// Blocks [0,166): weight split/pack (kprep body verbatim).
// Blocks [166,422): h1 = relu(x@W1.T+b1) (k1a body verbatim).
// Zero data dependence between halves; consumers (gemmS/kl34max/mega2) are
// later in stream order. Saves one launch gap; prep (memory-bound) overlaps
// k1a (VALU-bound) on the CUs.
__global__ __launch_bounds__(256, 2) void kprep_k1a(
    PrepAll pa,
    const float* __restrict__ x, const float* __restrict__ W1, const float* __restrict__ b1,
    bf16_t* __restrict__ h1h, bf16_t* __restrict__ h1l) {
  if (blockIdx.x < 166) {
    int blk = blockIdx.x, i = 0;
    while (blk >= pa.seg[i].nblk) { blk -= pa.seg[i].nblk; ++i; }
    const PrepSeg sg = pa.seg[i];
    int t8 = blk * 256 + threadIdx.x;
    int l = t8 & 63;
    int rest = t8 >> 6;
    int NKC = sg.K >> 4;
    int kc = rest % NKC, st = rest / NKC;
    int n = st * 32 + (l & 31);
    int k0 = kc * 16 + (l >> 5) * 8;
    const float* src = sg.src + (size_t)n * sg.SW + k0;
    bf16x8 hv, lv;
#pragma unroll
    for (int j = 0; j < 8; ++j) {
      float v = src[j];
      bf16_t h = (bf16_t)v;
      hv[j] = h; lv[j] = (bf16_t)(v - (float)h);
    }
    *(bf16x8*)(sg.h + (size_t)t8 * 8) = hv;
    *(bf16x8*)(sg.l + (size_t)t8 * 8) = lv;
  } else {
    int p = (blockIdx.x - 166) * 256 + threadIdx.x;
    float x0 = x[p * 3 + 0], x1 = x[p * 3 + 1], x2 = x[p * 3 + 2];
    int b = p >> 7, mi = (p >> 5) & 3, p31 = p & 31;
#pragma unroll
    for (int kc = 0; kc < 4; ++kc)
#pragma unroll
      for (int hbw = 0; hbw < 2; ++hbw) {
        bf16x8 hv, lv;
#pragma unroll
        for (int j = 0; j < 8; ++j) {
          int c = kc * 16 + hbw * 8 + j;
          float v = relu(fmaf(W1[c * 3], x0, fmaf(W1[c * 3 + 1], x1, fmaf(W1[c * 3 + 2], x2, b1[c]))));
          bf16_t h = (bf16_t)v;
          hv[j] = h; lv[j] = (bf16_t)(v - (float)h);
        }
        size_t off = (((size_t)(b * 4 + kc) * 4 + mi) * 64 + hbw * 32 + p31) * 8;
        *(bf16x8*)(h1h + off) = hv;
        *(bf16x8*)(h1l + off) = lv;
      }
  }
}

// ============ shared epilogue helpers
struct Oct { bf16x8 h0, l0, h1, l1; };
__device__ __forceinline__ Oct epi_pack(const f32x16& accv, int hb) {
  float a[16], rcv[8];
#pragma unroll
  for (int r = 0; r < 16; ++r) a[r] = relu(accv[r]);
#pragma unroll
  for (int j = 0; j < 8; ++j) rcv[j] = __shfl_xor(hb ? a[j] : a[8 + j], 32);
  float o0[8], o1[8];
#pragma unroll
  for (int j = 0; j < 4; ++j) {
    o0[j]     = hb ? rcv[j]     : a[j];
    o0[4 + j] = hb ? a[8 + j]   : rcv[j];
    o1[j]     = hb ? rcv[4 + j] : a[4 + j];
    o1[4 + j] = hb ? a[12 + j]  : rcv[4 + j];
  }
  Oct o;
#pragma unroll
  for (int j = 0; j < 8; ++j) {
    bf16_t x0 = (bf16_t)o0[j]; o.h0[j] = x0; o.l0[j] = (bf16_t)(o0[j] - (float)x0);
    bf16_t x1 = (bf16_t)o1[j]; o.h1[j] = x1; o.l1[j] = (bf16_t)(o1[j] - (float)x1);
  }
  return o;
}

__device__ __forceinline__ void epi_store_lds(const Oct& o, bf16_t* H, bf16_t* L, int ob, int p31) {
  *(bf16x8*)(H + (ob + p31) * 8)      = o.h0;
  *(bf16x8*)(H + (ob + 32 + p31) * 8) = o.h1;
  *(bf16x8*)(L + (ob + p31) * 8)      = o.l0;
  *(bf16x8*)(L + (ob + 32 + p31) * 8) = o.l1;
}

__device__ __forceinline__ void binit2(f32x16 acc[2], const float* bias, int base, int hb) {
#pragma unroll
  for (int r = 0; r < 16; ++r) {
    float bv = bias[base + 8 * (r >> 2) + 4 * hb + (r & 3)];
    acc[0][r] = bv; acc[1][r] = bv;
  }
}

// ============ gemmS: D = W·X^T, 3-term split 32x32x16 bf16 MFMA (L2 only)
template <int PB, int K, int MODE>
__global__ __launch_bounds__(256, 3) void gemmS(
    const bf16_t* __restrict__ Ah, const bf16_t* __restrict__ Al,
    const bf16_t* __restrict__ Wh, const bf16_t* __restrict__ Wl,
    const float* __restrict__ bias, int nko,
    bf16_t* __restrict__ Oh, bf16_t* __restrict__ Ol,
    float* __restrict__ aux, const float* __restrict__ w8, const float* __restrict__ b8) {
  constexpr int WC = 4 / PB;
  constexpr int NKC = K / 16;
  constexpr int KG = 2;
  constexpr int NG = NKC / KG;
  __shared__ bf16_t smem[2][PB][2][KG * 2048];

  int tid = threadIdx.x;
  int lane = tid & 63;
  int w = __builtin_amdgcn_readfirstlane(tid >> 6);
  int rg = w / WC, cw = w % WC;
  int hb = lane >> 5, p31 = lane & 31;
  int bx = blockIdx.x;
  int st0 = blockIdx.y * WC + cw;
  int bblk = bx * PB + rg;

  f32x16 acc[4];
#pragma unroll
  for (int r = 0; r < 16; ++r) {
    float bv = bias[st0 * 32 + 8 * (r >> 2) + 4 * hb + (r & 3)];
#pragma unroll
    for (int mi = 0; mi < 4; ++mi) acc[mi][r] = bv;
  }

  auto stage = [&](int buf, int g) {
#pragma unroll
    for (int i = 0; i < PB * 4; ++i) {
      int u = i * 256 + tid;
      int rgs = u >> 10, rem = u & 1023;
      int t = rem >> 9, inner = rem & 511;
      const bf16_t* src = (t ? Al : Ah) +
          ((size_t)(bx * PB + rgs) * NKC + g * KG) * 2048 + inner * 8;
      *(bf16x8*)&smem[buf][rgs][t][inner * 8] = *(const bf16x8*)src;
    }
  };

  bf16x8 wch[KG], wcl[KG], wnh[KG], wnl[KG];
  auto wload = [&](int g, bf16x8* h, bf16x8* l) {
#pragma unroll
    for (int kcl = 0; kcl < KG; ++kcl) {
      size_t wo = (((size_t)st0 * NKC + g * KG + kcl) * 64 + lane) * 8;
      h[kcl] = *(const bf16x8*)(Wh + wo);
      l[kcl] = *(const bf16x8*)(Wl + wo);
    }
  };

  auto compute = [&](int buf, bf16x8* h, bf16x8* l) {
#pragma unroll
    for (int kcl = 0; kcl < KG; ++kcl)
#pragma unroll
      for (int mi = 0; mi < 4; ++mi) {
        const bf16_t* xp = &smem[buf][rg][0][((kcl * 4 + mi) * 64 + lane) * 8];
        bf16x8 xh = *(const bf16x8*)xp;
        bf16x8 xl = *(const bf16x8*)(xp + KG * 2048);
        acc[mi] = MFMA32(h[kcl], xh, acc[mi]);
        acc[mi] = MFMA32(l[kcl], xh, acc[mi]);
        acc[mi] = MFMA32(h[kcl], xl, acc[mi]);
      }
  };

  stage(0, 0);
  wload(0, wch, wcl);
  for (int g = 0; g < NG; ++g) {
    __syncthreads();
    if (g + 1 < NG) {
      stage((g + 1) & 1, g + 1);
      wload(g + 1, wnh, wnl);
    }
    compute(g & 1, wch, wcl);
#pragma unroll
    for (int kcl = 0; kcl < KG; ++kcl) { wch[kcl] = wnh[kcl]; wcl[kcl] = wnl[kcl]; }
  }

  if constexpr (MODE == 0) {
#pragma unroll
    for (int mi = 0; mi < 4; ++mi) {
      Oct o = epi_pack(acc[mi], hb);
      int kco = st0 * 2 + hb;
      size_t ob = ((size_t)(bblk * nko + kco) * 4 + mi) * 64;
      *(bf16x8*)(Oh + (ob + p31) * 8)      = o.h0;
      *(bf16x8*)(Ol + (ob + p31) * 8)      = o.l0;
      *(bf16x8*)(Oh + (ob + 32 + p31) * 8) = o.h1;
      *(bf16x8*)(Ol + (ob + 32 + p31) * 8) = o.l1;
    }
  } else if constexpr (MODE == 1) {
#pragma unroll
    for (int r = 0; r < 16; ++r) {
      float m = relu(acc[0][r]);
#pragma unroll
      for (int mi = 1; mi < 4; ++mi) m = fmaxf(m, relu(acc[mi][r]));
#pragma unroll
      for (int off = 1; off < 32; off <<= 1) m = fmaxf(m, __shfl_xor(m, off));
      if (p31 == 0)
        aux[(size_t)bx * 1024 + st0 * 32 + 8 * (r >> 2) + 4 * hb + (r & 3)] = m;
    }
  } else {
    __shared__ float sp[4][128];
    float w8v[16];
#pragma unroll
    for (int r = 0; r < 16; ++r) w8v[r] = w8[st0 * 32 + 8 * (r >> 2) + 4 * hb + (r & 3)];
#pragma unroll
    for (int mi = 0; mi < 4; ++mi) {
      float s = 0.f;
#pragma unroll
      for (int r = 0; r < 16; ++r) s = fmaf(relu(acc[mi][r]), w8v[r], s);
      s += __shfl_xor(s, 32);
      if (hb == 0) sp[w][mi * 32 + p31] = s;
    }
    __syncthreads();
    if (tid < 128)
      aux[(size_t)bx * 128 + tid] = sp[0][tid] + sp[1][tid] + sp[2][tid] + sp[3][tid] + b8[0];
  }
}

// ============ kl34max v4 (R14 verbatim, measured 76.4 us): FUSED L3+L4,
// 2 tiles/block, barrier-free per-wave DMA staging; gpart output restored
// (R15 atomicMax regressed: contended atomics poison the counted-vmcnt waits).
__global__ __launch_bounds__(512, 1) void kl34max(
    const bf16_t* __restrict__ h2h, const bf16_t* __restrict__ h2l,
    const bf16_t* __restrict__ W3h, const bf16_t* __restrict__ W3l,
    const float* __restrict__ b3,
    const bf16_t* __restrict__ Wh, const bf16_t* __restrict__ Wl,
    const float* __restrict__ bias, float* __restrict__ gpart) {
  __shared__ __align__(16) bf16_t sA[81920];  // y3 [0,65536); wq [65536,81920)
  bf16_t* wq = sA + 65536;
  int tid = threadIdx.x, lane = tid & 63;
  int w = __builtin_amdgcn_readfirstlane(tid >> 6);   // 0..7
  int w3 = w & 3, t = w >> 2;                         // strip-slot, tile
  int hb = lane >> 5, p31 = lane & 31;
  int bx = blockIdx.x;
  int pb = bx * 2 + t;
  int rot = (bx >> 2) & 7;
  bf16_t* sT = sA + t * 32768;
  bf16_t* wbuf = wq + w * 2048;  // per-wave 4 KB: 2 buffers x (512 el h + 512 el l)

  // ---- phase 1: y3(tile t) = relu(h2@W3.T+b3) -> LDS. h2 B-frags for mi=w3.
  {
    bf16x8 hx[4], lx[4];
#pragma unroll
    for (int kc = 0; kc < 4; ++kc) {
      size_t so = (((size_t)(pb * 4 + kc) * 4 + w3) * 64 + lane) * 8;
      hx[kc] = *(const bf16x8*)(h2h + so);
      lx[kc] = *(const bf16x8*)(h2l + so);
    }
#pragma unroll
    for (int spr = 0; spr < 2; ++spr) {
      f32x16 a3[2];
#pragma unroll
      for (int s = 0; s < 2; ++s) {
        int st = spr * 2 + s;
#pragma unroll
        for (int r = 0; r < 16; ++r)
          a3[s][r] = b3[st * 32 + 8 * (r >> 2) + 4 * hb + (r & 3)];
      }
#pragma unroll
      for (int kc = 0; kc < 4; ++kc)
#pragma unroll
        for (int s = 0; s < 2; ++s) {
          int st = spr * 2 + s;
          size_t wo = ((size_t)(st * 4 + kc) * 64 + lane) * 8;
          bf16x8 wh3 = *(const bf16x8*)(W3h + wo);
          bf16x8 wl3 = *(const bf16x8*)(W3l + wo);
          a3[s] = MFMA32(wh3, hx[kc], a3[s]);
          a3[s] = MFMA32(wl3, hx[kc], a3[s]);
          a3[s] = MFMA32(wh3, lx[kc], a3[s]);
        }
#pragma unroll
      for (int s = 0; s < 2; ++s) {
        int st = spr * 2 + s;
        Oct o = epi_pack(a3[s], hb);
        epi_store_lds(o, sT, sT + 16384, ((st * 2 + hb) * 4 + w3) * 64, p31);
      }
    }
  }
  __syncthreads();  // y3 ready — the ONLY block-wide barrier

  // ---- phase 2: barrier-free per-wave weight pipeline over 64 (j,kc) phases
  auto issueW = [&](int u) {
    int jj = u >> 3, kc = u & 7;
    int st = ((jj + rot) & 7) * 4 + w3;
    const bf16_t* gph = Wh + ((size_t)(st * 8 + kc) * 64 + lane) * 8;
    const bf16_t* gpl = Wl + ((size_t)(st * 8 + kc) * 64 + lane) * 8;
    bf16_t* lp = wbuf + (u & 1) * 1024;  // wave-uniform base; DMA writes lane*16B
    __builtin_amdgcn_global_load_lds(
        (const __attribute__((address_space(1))) void*)gph,
        (__attribute__((address_space(3))) void*)lp, 16, 0, 0);
    __builtin_amdgcn_global_load_lds(
        (const __attribute__((address_space(1))) void*)gpl,
        (__attribute__((address_space(3))) void*)(lp + 512), 16, 0, 0);
  };
  issueW(0);

  f32x16 acc[4];
#pragma unroll 1
  for (int u = 0; u < 64; ++u) {
    if (u + 1 < 64) {
      issueW(u + 1);
      asm volatile("s_waitcnt vmcnt(2)" ::: "memory");  // DMA(u) landed; DMA(u+1) in flight
    } else {
      asm volatile("s_waitcnt vmcnt(0)" ::: "memory");
    }
    __builtin_amdgcn_sched_barrier(0);  // rule #18: pin reads after the wait
    int jj = u >> 3, kc = u & 7;
    int st = ((jj + rot) & 7) * 4 + w3;
    if (kc == 0) {
#pragma unroll
      for (int r = 0; r < 16; ++r) {
        float bv = bias[st * 32 + 8 * (r >> 2) + 4 * hb + (r & 3)];
#pragma unroll
        for (int mi = 0; mi < 4; ++mi) acc[mi][r] = bv;
      }
    }
    const bf16_t* wb = wbuf + (u & 1) * 1024;
    bf16x8 cwh = *(const bf16x8*)(wb + lane * 8);
    bf16x8 cwl = *(const bf16x8*)(wb + 512 + lane * 8);
    __builtin_amdgcn_s_setprio(1);
#pragma unroll
    for (int mi = 0; mi < 4; ++mi) {
      const bf16_t* xp = sT + ((kc * 4 + mi) * 64 + lane) * 8;
      bf16x8 xh = *(const bf16x8*)xp;
      bf16x8 xl = *(const bf16x8*)(xp + 16384);
      acc[mi] = MFMA32(cwh, xh, acc[mi]);
      acc[mi] = MFMA32(cwl, xh, acc[mi]);
      acc[mi] = MFMA32(cwh, xl, acc[mi]);
    }
    __builtin_amdgcn_s_setprio(0);
    if (kc == 7) {
#pragma unroll
      for (int r = 0; r < 16; ++r) {
        float m = fmaxf(fmaxf(acc[0][r], acc[1][r]), fmaxf(acc[2][r], acc[3][r]));
        m = fmaxf(m, 0.f);  // relu folded into the max
#pragma unroll
        for (int off = 1; off < 32; off <<= 1) m = fmaxf(m, __shfl_xor(m, off));
        if (p31 == 0)
          gpart[(size_t)pb * 1024 + st * 32 + 8 * (r >> 2) + 4 * hb + (r & 3)] = m;
      }
    }
  }
}

// ============ kgmax: g[c] = max over 512 rows of gpart[512][1024]
__global__ __launch_bounds__(256) void kgmax(const float* __restrict__ gpart, float* __restrict__ g) {
  int t = blockIdx.x * 256 + threadIdx.x;  // 8192 threads
  int c = t & 1023, rg = t >> 10;
  const float* gp = gpart + (size_t)rg * 64 * 1024 + c;
  float m = 0.f;
#pragma unroll 8
  for (int r = 0; r < 64; ++r) m = fmaxf(m, gp[(size_t)r * 1024]);
  atomicMax((unsigned int*)(g + c), __float_as_uint(m));  // all values >= 0
}

// ============ kc5 v3: c5[c] = W5[c][64:1088] @ g + b5[c], COALESCED.
// 32 blocks x 4 waves = 128 waves x 4 channels = 512 = L5 output count.
__global__ __launch_bounds__(256) void kc5(
    const float* __restrict__ W5, const float* __restrict__ b5,
    const float* __restrict__ g, float* __restrict__ c5) {
  int lane = threadIdx.x & 63;
  int wv = blockIdx.x * 4 + (threadIdx.x >> 6);  // 128 waves
  float gv[16];
#pragma unroll
  for (int k = 0; k < 16; ++k) gv[k] = g[k * 64 + lane];
#pragma unroll
  for (int i = 0; i < 4; ++i) {
    int c = wv * 4 + i;  // 0..511
    const float* wrow = W5 + (size_t)c * 1088 + 64;
    float acc = 0.f;
#pragma unroll
    for (int k = 0; k < 16; ++k) acc = fmaf(wrow[k * 64 + lane], gv[k], acc);
#pragma unroll
    for (int off = 1; off < 64; off <<= 1) acc += __shfl_xor(acc, off);
    if (lane == 0) c5[c] = acc + b5[c];
  }
}

// ======================================================================
// mega2 v2 (R14 verbatim): h2 -> z5 -> z6 -> z7 -> out, 64-pt blocks.
// ======================================================================

__global__ __launch_bounds__(256, 2) void mega2(
    const bf16_t* __restrict__ h2gh, const bf16_t* __restrict__ h2gl,
    const bf16_t* __restrict__ W5h, const bf16_t* __restrict__ W5l, const float* __restrict__ c5,
    const bf16_t* __restrict__ W6h, const bf16_t* __restrict__ W6l, const float* __restrict__ b6,
    const bf16_t* __restrict__ W7h, const bf16_t* __restrict__ W7l, const float* __restrict__ b7,
    const float* __restrict__ w8, const float* __restrict__ b8v, float* __restrict__ out) {
  __shared__ __align__(16) bf16_t smem[32768];
  __shared__ float sp[4][64];
  int tid = threadIdx.x, lane = tid & 63;
  int w = __builtin_amdgcn_readfirstlane(tid >> 6);
  int hb = lane >> 5, p31 = lane & 31;
  int b = blockIdx.x;
  int B = b >> 1, half = b & 1;

  bf16x8 xh[4][2], xl[4][2];
#pragma unroll
  for (int kc = 0; kc < 4; ++kc)
#pragma unroll
    for (int mi = 0; mi < 2; ++mi) {
      size_t so = (((size_t)((B * 4 + kc) * 4 + half * 2 + mi)) * 64 + lane) * 8;
      xh[kc][mi] = *(const bf16x8*)(h2gh + so);
      xl[kc][mi] = *(const bf16x8*)(h2gl + so);
    }

  f32x16 z6a[2][2];
#pragma unroll
  for (int s = 0; s < 2; ++s)
#pragma unroll
    for (int r = 0; r < 16; ++r) {
      float bv = b6[(w * 2 + s) * 32 + 8 * (r >> 2) + 4 * hb + (r & 3)];
      z6a[s][0][r] = bv; z6a[s][1][r] = bv;
    }

  bf16x8 w5h[4], w5l[4];
  auto w5load = [&](int g) {
#pragma unroll
    for (int kc = 0; kc < 4; ++kc) {
      size_t wo = (((size_t)(g * 4 + w) * 4 + kc) * 64 + lane) * 8;
      w5h[kc] = *(const bf16x8*)(W5h + wo);
      w5l[kc] = *(const bf16x8*)(W5l + wo);
    }
  };
  w5load(0);

  bf16x8 cwh[2], cwl[2], nwh[2], nwl[2];
  auto w6load = [&](int g, int kc, bf16x8* hh, bf16x8* ll) {
#pragma unroll
    for (int s = 0; s < 2; ++s) {
      size_t wo = ((size_t)((w * 2 + s) * 32 + g * 8 + kc) * 64 + lane) * 8;
      hh[s] = *(const bf16x8*)(W6h + wo);
      ll[s] = *(const bf16x8*)(W6l + wo);
    }
  };

  for (int g5 = 0; g5 < 4; ++g5) {
    bf16_t* zbuf = smem + (g5 & 1) * 16384;
    int st5 = g5 * 4 + w;
    f32x16 a5[2];
    binit2(a5, c5, st5 * 32, hb);
    __builtin_amdgcn_s_setprio(1);
#pragma unroll
    for (int kc = 0; kc < 4; ++kc) {
#pragma unroll
      for (int mi = 0; mi < 2; ++mi) a5[mi] = MFMA32(w5h[kc], xh[kc][mi], a5[mi]);
#pragma unroll
      for (int mi = 0; mi < 2; ++mi) a5[mi] = MFMA32(w5l[kc], xh[kc][mi], a5[mi]);
#pragma unroll
      for (int mi = 0; mi < 2; ++mi) a5[mi] = MFMA32(w5h[kc], xl[kc][mi], a5[mi]);
    }
    __builtin_amdgcn_s_setprio(0);
    if (g5 < 3) w5load(g5 + 1);
#pragma unroll
    for (int mi = 0; mi < 2; ++mi) {
      Oct o = epi_pack(a5[mi], hb);
      epi_store_lds(o, zbuf, zbuf + 8192, ((w * 2 + hb) * 2 + mi) * 64, p31);
    }
    w6load(g5, 0, cwh, cwl);
    __syncthreads();
#pragma unroll
    for (int kc = 0; kc < 8; ++kc) {
      if (kc < 7) w6load(g5, kc + 1, nwh, nwl);
      bf16x8 zxh[2], zxl[2];
#pragma unroll
      for (int mi = 0; mi < 2; ++mi) {
        const bf16_t* xp = zbuf + ((kc * 2 + mi) * 64 + lane) * 8;
        zxh[mi] = *(const bf16x8*)xp;
        zxl[mi] = *(const bf16x8*)(xp + 8192);
      }
      __builtin_amdgcn_s_setprio(1);
#pragma unroll
      for (int s = 0; s < 2; ++s)
#pragma unroll
        for (int mi = 0; mi < 2; ++mi) z6a[s][mi] = MFMA32(cwh[s], zxh[mi], z6a[s][mi]);
#pragma unroll
      for (int s = 0; s < 2; ++s)
#pragma unroll
        for (int mi = 0; mi < 2; ++mi) z6a[s][mi] = MFMA32(cwl[s], zxh[mi], z6a[s][mi]);
#pragma unroll
      for (int s = 0; s < 2; ++s)
#pragma unroll
        for (int mi = 0; mi < 2; ++mi) z6a[s][mi] = MFMA32(cwh[s], zxl[mi], z6a[s][mi]);
      __builtin_amdgcn_s_setprio(0);
#pragma unroll
      for (int s = 0; s < 2; ++s) { cwh[s] = nwh[s]; cwl[s] = nwl[s]; }
    }
  }
  __syncthreads();
#pragma unroll
  for (int s = 0; s < 2; ++s) {
    int kcb = (w * 2 + s) * 2 + hb;
#pragma unroll
    for (int mi = 0; mi < 2; ++mi) {
      Oct o = epi_pack(z6a[s][mi], hb);
      epi_store_lds(o, smem, smem + 16384, (kcb * 2 + mi) * 64, p31);
    }
  }
  bf16x8 a7wh, a7wl, n7h, n7l;
  {
    size_t wo = ((size_t)(w * 16) * 64 + lane) * 8;
    a7wh = *(const bf16x8*)(W7h + wo);
    a7wl = *(const bf16x8*)(W7l + wo);
  }
  __syncthreads();
  f32x16 a7[2];
  binit2(a7, b7, w * 32, hb);
#pragma unroll
  for (int kc = 0; kc < 16; ++kc) {
    if (kc < 15) {
      size_t wo = ((size_t)(w * 16 + kc + 1) * 64 + lane) * 8;
      n7h = *(const bf16x8*)(W7h + wo);
      n7l = *(const bf16x8*)(W7l + wo);
    }
    bf16x8 zxh[2], zxl[2];
#pragma unroll
    for (int mi = 0; mi < 2; ++mi) {
      const bf16_t* xp = smem + ((kc * 2 + mi) * 64 + lane) * 8;
      zxh[mi] = *(const bf16x8*)xp;
      zxl[mi] = *(const bf16x8*)(xp + 16384);
    }
    __builtin_amdgcn_s_setprio(1);
#pragma unroll
    for (int mi = 0; mi < 2; ++mi) a7[mi] = MFMA32(a7wh, zxh[mi], a7[mi]);
#pragma unroll
    for (int mi = 0; mi < 2; ++mi) a7[mi] = MFMA32(a7wl, zxh[mi], a7[mi]);
#pragma unroll
    for (int mi = 0; mi < 2; ++mi) a7[mi] = MFMA32(a7wh, zxl[mi], a7[mi]);
    __builtin_amdgcn_s_setprio(0);
    a7wh = n7h; a7wl = n7l;
  }
  float w8v[16];
#pragma unroll
  for (int r = 0; r < 16; ++r) w8v[r] = w8[w * 32 + 8 * (r >> 2) + 4 * hb + (r & 3)];
#pragma unroll
  for (int mi = 0; mi < 2; ++mi) {
    float s = 0.f;
#pragma unroll
    for (int r = 0; r < 16; ++r) s = fmaf(relu(a7[mi][r]), w8v[r], s);
    s += __shfl_xor(s, 32);
    if (hb == 0) sp[w][mi * 32 + p31] = s;
  }
  __syncthreads();
  if (tid < 64)
    out[b * 64 + tid] = sp[0][tid] + sp[1][tid] + sp[2][tid] + sp[3][tid] + b8v[0];
}

extern "C" void kernel_launch(void* const* d_in, const int* in_sizes, int n_in,
                              void* d_out, int out_size, void* d_ws, size_t ws_size,
                              hipStream_t stream) {
  const float* x  = (const float*)d_in[0];
  const float* W1 = (const float*)d_in[1];  const float* b1 = (const float*)d_in[2];
  const float* W2 = (const float*)d_in[3];  const float* b2 = (const float*)d_in[4];
  const float* W3 = (const float*)d_in[5];  const float* b3 = (const float*)d_in[6];
  const float* W4 = (const float*)d_in[7];  const float* b4 = (const float*)d_in[8];
  const float* W5 = (const float*)d_in[9];  const float* b5 = (const float*)d_in[10];
  const float* W6 = (const float*)d_in[11]; const float* b6 = (const float*)d_in[12];
  const float* W7 = (const float*)d_in[13]; const float* b7 = (const float*)d_in[14];
  const float* W8 = (const float*)d_in[15]; const float* b8 = (const float*)d_in[16];
  float* out = (float*)d_out;

  // Workspace overlays:
  //   h2 pair [128,136)+[136,144)  L2->kl34max,mega2
  //   h1 pair [144,152)+[152,160)  k1a->L2
  //   gpart [208,210), g/c5 [210,..), weight frags after
  const size_t MB = 1ull << 20;
  char* ws = (char*)d_ws;
  bf16_t* h2h = (bf16_t*)(ws + 128 * MB);  bf16_t* h2l = (bf16_t*)(ws + 136 * MB);
  bf16_t* h1h = (bf16_t*)(ws + 144 * MB);  bf16_t* h1l = (bf16_t*)(ws + 152 * MB);
  float* gpart = (float*)(ws + 208 * MB);
  float* g     = (float*)(ws + 210 * MB);
  float* c5    = (float*)(ws + 210 * MB + 4096);
  char* wb = ws + 210 * MB + 65536;
  bf16_t* W2h = (bf16_t*)(wb);             bf16_t* W2l = (bf16_t*)(wb + 8192);
  bf16_t* W3h = (bf16_t*)(wb + 16384);     bf16_t* W3l = (bf16_t*)(wb + 32768);
  bf16_t* W4h = (bf16_t*)(wb + 49152);     bf16_t* W4l = (bf16_t*)(wb + 311296);
  bf16_t* W5h = (bf16_t*)(wb + 573440);    bf16_t* W5l = (bf16_t*)(wb + 638976);
  bf16_t* W6h = (bf16_t*)(wb + 704512);    bf16_t* W6l = (bf16_t*)(wb + 966656);
  bf16_t* W7h = (bf16_t*)(wb + 1228800);   bf16_t* W7l = (bf16_t*)(wb + 1294336);

  hipMemsetAsync(g, 0, 1024 * sizeof(float), stream);  // max identity (relu outputs >= 0)

  PrepAll pa;
  pa.seg[0] = {W2, W2h, W2l, 64, 64, 2};
  pa.seg[1] = {W3, W3h, W3l, 64, 64, 4};
  pa.seg[2] = {W4, W4h, W4l, 128, 128, 64};
  pa.seg[3] = {W5, W5h, W5l, 1088, 64, 16};   // W5[:, :64]
  pa.seg[4] = {W6, W6h, W6l, 512, 512, 64};
  pa.seg[5] = {W7, W7h, W7l, 256, 256, 16};

  kprep_k1a<<<422, 256, 0, stream>>>(pa, x, W1, b1, h1h, h1l);                // prep + L1 fused
  gemmS<2, 64, 0><<<dim3(256, 1), 256, 0, stream>>>(
      h1h, h1l, W2h, W2l, b2, 4, h2h, h2l, nullptr, nullptr, nullptr);        // L2
  kl34max<<<256, 512, 0, stream>>>(h2h, h2l, W3h, W3l, b3, W4h, W4l, b4, gpart);  // L3+L4+max
  kgmax<<<32, 256, 0, stream>>>(gpart, g);
  kc5<<<32, 256, 0, stream>>>(W5, b5, g, c5);
  mega2<<<1024, 256, 0, stream>>>(h2h, h2l, W5h, W5l, c5, W6h, W6l, b6,
                                  W7h, W7l, b7, W8, b8, out);                 // L5..L8 fused
}

// Round 17
// 245.438 us; speedup vs baseline: 1.1230x; 1.0176x over previous
//
#include <hip/hip_runtime.h>

#define NPTS 65536

typedef __bf16 bf16_t;
typedef __bf16 bf16x8 __attribute__((ext_vector_type(8)));
typedef float f32x16 __attribute__((ext_vector_type(16)));

#define MFMA32(A, B, C) __builtin_amdgcn_mfma_f32_32x32x16_bf16(A, B, C, 0, 0, 0)

__device__ __forceinline__ float relu(float v) { return v > 0.f ? v : 0.f; }

// ======================================================================
// Layouts (128-pt blocks, 4 mi slots):
// Activation (C ch): octet idx = ((b*(C/16)+kc)*4+mi)*64 + l
//   point = b*128 + mi*32 + (l&31); channel = kc*16 + (l>>5)*8 + j
// Weight (N x K): octet idx = (st*(K/16)+kc)*64 + l; n = st*32+(l&31); k = kc*16+(l>>5)*8+j
// ======================================================================

struct PrepSeg { const float* src; bf16_t* h; bf16_t* l; int SW; int K; int nblk; };
struct PrepAll { PrepSeg seg[6]; };

// ============ kprep_k1a: FUSED independent front-end work (one dispatch).
// Blocks [0,166): weight split/pack. Blocks [166,422): h1 = relu(x@W1.T+b1).
__global__ __launch_bounds__(256, 2) void kprep_k1a(
    PrepAll pa,
    const float* __restrict__ x, const float* __restrict__ W1, const float* __restrict__ b1,
    bf16_t* __restrict__ h1h, bf16_t* __restrict__ h1l) {
  if (blockIdx.x < 166) {
    int blk = blockIdx.x, i = 0;
    while (blk >= pa.seg[i].nblk) { blk -= pa.seg[i].nblk; ++i; }
    const PrepSeg sg = pa.seg[i];
    int t8 = blk * 256 + threadIdx.x;
    int l = t8 & 63;
    int rest = t8 >> 6;
    int NKC = sg.K >> 4;
    int kc = rest % NKC, st = rest / NKC;
    int n = st * 32 + (l & 31);
    int k0 = kc * 16 + (l >> 5) * 8;
    const float* src = sg.src + (size_t)n * sg.SW + k0;
    bf16x8 hv, lv;
#pragma unroll
    for (int j = 0; j < 8; ++j) {
      float v = src[j];
      bf16_t h = (bf16_t)v;
      hv[j] = h; lv[j] = (bf16_t)(v - (float)h);
    }
    *(bf16x8*)(sg.h + (size_t)t8 * 8) = hv;
    *(bf16x8*)(sg.l + (size_t)t8 * 8) = lv;
  } else {
    int p = (blockIdx.x - 166) * 256 + threadIdx.x;
    float x0 = x[p * 3 + 0], x1 = x[p * 3 + 1], x2 = x[p * 3 + 2];
    int b = p >> 7, mi = (p >> 5) & 3, p31 = p & 31;
#pragma unroll
    for (int kc = 0; kc < 4; ++kc)
#pragma unroll
      for (int hbw = 0; hbw < 2; ++hbw) {
        bf16x8 hv, lv;
#pragma unroll
        for (int j = 0; j < 8; ++j) {
          int c = kc * 16 + hbw * 8 + j;
          float v = relu(fmaf(W1[c * 3], x0, fmaf(W1[c * 3 + 1], x1, fmaf(W1[c * 3 + 2], x2, b1[c]))));
          bf16_t h = (bf16_t)v;
          hv[j] = h; lv[j] = (bf16_t)(v - (float)h);
        }
        size_t off = (((size_t)(b * 4 + kc) * 4 + mi) * 64 + hbw * 32 + p31) * 8;
        *(bf16x8*)(h1h + off) = hv;
        *(bf16x8*)(h1l + off) = lv;
      }
  }
}

// ============ shared epilogue helpers
struct Oct { bf16x8 h0, l0, h1, l1; };
__device__ __forceinline__ Oct epi_pack(const f32x16& accv, int hb) {
  float a[16], rcv[8];
#pragma unroll
  for (int r = 0; r < 16; ++r) a[r] = relu(accv[r]);
#pragma unroll
  for (int j = 0; j < 8; ++j) rcv[j] = __shfl_xor(hb ? a[j] : a[8 + j], 32);
  float o0[8], o1[8];
#pragma unroll
  for (int j = 0; j < 4; ++j) {
    o0[j]     = hb ? rcv[j]     : a[j];
    o0[4 + j] = hb ? a[8 + j]   : rcv[j];
    o1[j]     = hb ? rcv[4 + j] : a[4 + j];
    o1[4 + j] = hb ? a[12 + j]  : rcv[4 + j];
  }
  Oct o;
#pragma unroll
  for (int j = 0; j < 8; ++j) {
    bf16_t x0 = (bf16_t)o0[j]; o.h0[j] = x0; o.l0[j] = (bf16_t)(o0[j] - (float)x0);
    bf16_t x1 = (bf16_t)o1[j]; o.h1[j] = x1; o.l1[j] = (bf16_t)(o1[j] - (float)x1);
  }
  return o;
}

__device__ __forceinline__ void epi_store_lds(const Oct& o, bf16_t* H, bf16_t* L, int ob, int p31) {
  *(bf16x8*)(H + (ob + p31) * 8)      = o.h0;
  *(bf16x8*)(H + (ob + 32 + p31) * 8) = o.h1;
  *(bf16x8*)(L + (ob + p31) * 8)      = o.l0;
  *(bf16x8*)(L + (ob + 32 + p31) * 8) = o.l1;
}

__device__ __forceinline__ void binit2(f32x16 acc[2], const float* bias, int base, int hb) {
#pragma unroll
  for (int r = 0; r < 16; ++r) {
    float bv = bias[base + 8 * (r >> 2) + 4 * hb + (r & 3)];
    acc[0][r] = bv; acc[1][r] = bv;
  }
}

// ============ gemmS: D = W·X^T, 3-term split 32x32x16 bf16 MFMA (L2 only)
template <int PB, int K, int MODE>
__global__ __launch_bounds__(256, 3) void gemmS(
    const bf16_t* __restrict__ Ah, const bf16_t* __restrict__ Al,
    const bf16_t* __restrict__ Wh, const bf16_t* __restrict__ Wl,
    const float* __restrict__ bias, int nko,
    bf16_t* __restrict__ Oh, bf16_t* __restrict__ Ol,
    float* __restrict__ aux, const float* __restrict__ w8, const float* __restrict__ b8) {
  constexpr int WC = 4 / PB;
  constexpr int NKC = K / 16;
  constexpr int KG = 2;
  constexpr int NG = NKC / KG;
  __shared__ bf16_t smem[2][PB][2][KG * 2048];

  int tid = threadIdx.x;
  int lane = tid & 63;
  int w = __builtin_amdgcn_readfirstlane(tid >> 6);
  int rg = w / WC, cw = w % WC;
  int hb = lane >> 5, p31 = lane & 31;
  int bx = blockIdx.x;
  int st0 = blockIdx.y * WC + cw;
  int bblk = bx * PB + rg;

  f32x16 acc[4];
#pragma unroll
  for (int r = 0; r < 16; ++r) {
    float bv = bias[st0 * 32 + 8 * (r >> 2) + 4 * hb + (r & 3)];
#pragma unroll
    for (int mi = 0; mi < 4; ++mi) acc[mi][r] = bv;
  }

  auto stage = [&](int buf, int g) {
#pragma unroll
    for (int i = 0; i < PB * 4; ++i) {
      int u = i * 256 + tid;
      int rgs = u >> 10, rem = u & 1023;
      int t = rem >> 9, inner = rem & 511;
      const bf16_t* src = (t ? Al : Ah) +
          ((size_t)(bx * PB + rgs) * NKC + g * KG) * 2048 + inner * 8;
      *(bf16x8*)&smem[buf][rgs][t][inner * 8] = *(const bf16x8*)src;
    }
  };

  bf16x8 wch[KG], wcl[KG], wnh[KG], wnl[KG];
  auto wload = [&](int g, bf16x8* h, bf16x8* l) {
#pragma unroll
    for (int kcl = 0; kcl < KG; ++kcl) {
      size_t wo = (((size_t)st0 * NKC + g * KG + kcl) * 64 + lane) * 8;
      h[kcl] = *(const bf16x8*)(Wh + wo);
      l[kcl] = *(const bf16x8*)(Wl + wo);
    }
  };

  auto compute = [&](int buf, bf16x8* h, bf16x8* l) {
#pragma unroll
    for (int kcl = 0; kcl < KG; ++kcl)
#pragma unroll
      for (int mi = 0; mi < 4; ++mi) {
        const bf16_t* xp = &smem[buf][rg][0][((kcl * 4 + mi) * 64 + lane) * 8];
        bf16x8 xh = *(const bf16x8*)xp;
        bf16x8 xl = *(const bf16x8*)(xp + KG * 2048);
        acc[mi] = MFMA32(h[kcl], xh, acc[mi]);
        acc[mi] = MFMA32(l[kcl], xh, acc[mi]);
        acc[mi] = MFMA32(h[kcl], xl, acc[mi]);
      }
  };

  stage(0, 0);
  wload(0, wch, wcl);
  for (int g = 0; g < NG; ++g) {
    __syncthreads();
    if (g + 1 < NG) {
      stage((g + 1) & 1, g + 1);
      wload(g + 1, wnh, wnl);
    }
    compute(g & 1, wch, wcl);
#pragma unroll
    for (int kcl = 0; kcl < KG; ++kcl) { wch[kcl] = wnh[kcl]; wcl[kcl] = wnl[kcl]; }
  }

  if constexpr (MODE == 0) {
#pragma unroll
    for (int mi = 0; mi < 4; ++mi) {
      Oct o = epi_pack(acc[mi], hb);
      int kco = st0 * 2 + hb;
      size_t ob = ((size_t)(bblk * nko + kco) * 4 + mi) * 64;
      *(bf16x8*)(Oh + (ob + p31) * 8)      = o.h0;
      *(bf16x8*)(Ol + (ob + p31) * 8)      = o.l0;
      *(bf16x8*)(Oh + (ob + 32 + p31) * 8) = o.h1;
      *(bf16x8*)(Ol + (ob + 32 + p31) * 8) = o.l1;
    }
  } else if constexpr (MODE == 1) {
#pragma unroll
    for (int r = 0; r < 16; ++r) {
      float m = relu(acc[0][r]);
#pragma unroll
      for (int mi = 1; mi < 4; ++mi) m = fmaxf(m, relu(acc[mi][r]));
#pragma unroll
      for (int off = 1; off < 32; off <<= 1) m = fmaxf(m, __shfl_xor(m, off));
      if (p31 == 0)
        aux[(size_t)bx * 1024 + st0 * 32 + 8 * (r >> 2) + 4 * hb + (r & 3)] = m;
    }
  } else {
    __shared__ float sp[4][128];
    float w8v[16];
#pragma unroll
    for (int r = 0; r < 16; ++r) w8v[r] = w8[st0 * 32 + 8 * (r >> 2) + 4 * hb + (r & 3)];
#pragma unroll
    for (int mi = 0; mi < 4; ++mi) {
      float s = 0.f;
#pragma unroll
      for (int r = 0; r < 16; ++r) s = fmaf(relu(acc[mi][r]), w8v[r], s);
      s += __shfl_xor(s, 32);
      if (hb == 0) sp[w][mi * 32 + p31] = s;
    }
    __syncthreads();
    if (tid < 128)
      aux[(size_t)bx * 128 + tid] = sp[0][tid] + sp[1][tid] + sp[2][tid] + sp[3][tid] + b8[0];
  }
}

// ============ kl34max v7: FUSED L3+L4, 2 tiles/block, 32 DOUBLE-KC phases with
// BLOCK-COOP weight staging. v4 post-mortem: per-phase fixed overhead (~2700 cyc
// vs 192 MFMA + 640 LDS) dominates -> halve phase count. Each phase stages 16 KB
// (2 kc x 4 strip-slots x h/l): every wave issues exactly 2 global_load_lds
// (unit = i*8+w -> sslot/q/part; wave-uniform dest). wq re-laid per-slot,
// double-buffered 2 x 16 KB = 32 KB (total LDS unchanged at 160 KiB). Sync per
// phase: {vmcnt(0) -> s_barrier -> issueW(u+1) -> compute} (R7's proven-correct
// skeleton; drain is ~free since DMAs had a full phase to land; issue-after-
// barrier makes buffer recycle WAR-safe). Sharing across tile-pair waves
// restores 1 request/line. MFMA order per (jj,kc) bit-identical to v4.
__global__ __launch_bounds__(512, 1) void kl34max(
    const bf16_t* __restrict__ h2h, const bf16_t* __restrict__ h2l,
    const bf16_t* __restrict__ W3h, const bf16_t* __restrict__ W3l,
    const float* __restrict__ b3,
    const bf16_t* __restrict__ Wh, const bf16_t* __restrict__ Wl,
    const float* __restrict__ bias, float* __restrict__ gpart) {
  __shared__ __align__(16) bf16_t sA[81920];  // y3 [0,65536); wq [65536,81920)
  bf16_t* wq = sA + 65536;
  int tid = threadIdx.x, lane = tid & 63;
  int w = __builtin_amdgcn_readfirstlane(tid >> 6);   // 0..7
  int w3 = w & 3, t = w >> 2;                         // strip-slot, tile
  int hb = lane >> 5, p31 = lane & 31;
  int bx = blockIdx.x;
  int pb = bx * 2 + t;
  int rot = (bx >> 2) & 7;
  bf16_t* sT = sA + t * 32768;

  // block-coop staging of one double-kc phase (16 KB; 2 wave-DMAs per wave)
  auto issueW = [&](int u) {
    int jj = u >> 2, kp = (u & 3) * 2;
#pragma unroll
    for (int i = 0; i < 2; ++i) {
      int unit = i * 8 + w;                 // 0..15, wave-uniform
      int sslot = unit & 3;                 // strip-slot staged
      int q     = (unit >> 2) & 1;          // kc within pair
      int part  = unit >> 3;                // 0=h, 1=l
      int st = ((jj + rot) & 7) * 4 + sslot;
      int kc = kp + q;
      const bf16_t* W = part ? Wl : Wh;
      const bf16_t* gp = W + ((size_t)(st * 8 + kc) * 64 + lane) * 8;
      bf16_t* lp = wq + (u & 1) * 8192 + (sslot * 4 + q * 2 + part) * 512;
      __builtin_amdgcn_global_load_lds(
          (const __attribute__((address_space(1))) void*)gp,
          (__attribute__((address_space(3))) void*)lp, 16, 0, 0);
    }
  };
  issueW(0);  // latency hides under all of phase 1

  // ---- phase 1: y3(tile t) = relu(h2@W3.T+b3) -> LDS. h2 B-frags for mi=w3.
  {
    bf16x8 hx[4], lx[4];
#pragma unroll
    for (int kc = 0; kc < 4; ++kc) {
      size_t so = (((size_t)(pb * 4 + kc) * 4 + w3) * 64 + lane) * 8;
      hx[kc] = *(const bf16x8*)(h2h + so);
      lx[kc] = *(const bf16x8*)(h2l + so);
    }
#pragma unroll
    for (int spr = 0; spr < 2; ++spr) {
      f32x16 a3[2];
#pragma unroll
      for (int s = 0; s < 2; ++s) {
        int st = spr * 2 + s;
#pragma unroll
        for (int r = 0; r < 16; ++r)
          a3[s][r] = b3[st * 32 + 8 * (r >> 2) + 4 * hb + (r & 3)];
      }
#pragma unroll
      for (int kc = 0; kc < 4; ++kc)
#pragma unroll
        for (int s = 0; s < 2; ++s) {
          int st = spr * 2 + s;
          size_t wo = ((size_t)(st * 4 + kc) * 64 + lane) * 8;
          bf16x8 wh3 = *(const bf16x8*)(W3h + wo);
          bf16x8 wl3 = *(const bf16x8*)(W3l + wo);
          a3[s] = MFMA32(wh3, hx[kc], a3[s]);
          a3[s] = MFMA32(wl3, hx[kc], a3[s]);
          a3[s] = MFMA32(wh3, lx[kc], a3[s]);
        }
#pragma unroll
      for (int s = 0; s < 2; ++s) {
        int st = spr * 2 + s;
        Oct o = epi_pack(a3[s], hb);
        epi_store_lds(o, sT, sT + 16384, ((st * 2 + hb) * 4 + w3) * 64, p31);
      }
    }
  }
  __syncthreads();  // y3 ready

  // ---- phase 2: 32 double-kc phases
  f32x16 acc[4];
#pragma unroll 1
  for (int u = 0; u < 32; ++u) {
    asm volatile("s_waitcnt vmcnt(0)" ::: "memory");  // my phase-u DMAs (+ older stores) done
    __builtin_amdgcn_sched_barrier(0);
    __builtin_amdgcn_s_barrier();                     // all waves' phase-u weights visible
    if (u + 1 < 32) issueW(u + 1);                    // post-barrier: recycled slot is dead
    int jj = u >> 2, kp = (u & 3) * 2;
    int stc = ((jj + rot) & 7) * 4 + w3;
    if ((u & 3) == 0) {
#pragma unroll
      for (int r = 0; r < 16; ++r) {
        float bv = bias[stc * 32 + 8 * (r >> 2) + 4 * hb + (r & 3)];
#pragma unroll
        for (int mi = 0; mi < 4; ++mi) acc[mi][r] = bv;
      }
    }
    const bf16_t* wb = wq + (u & 1) * 8192;
#pragma unroll
    for (int q = 0; q < 2; ++q) {
      int kc = kp + q;
      bf16x8 cwh = *(const bf16x8*)(wb + (w3 * 4 + q * 2) * 512 + lane * 8);
      bf16x8 cwl = *(const bf16x8*)(wb + (w3 * 4 + q * 2 + 1) * 512 + lane * 8);
      __builtin_amdgcn_s_setprio(1);
#pragma unroll
      for (int mi = 0; mi < 4; ++mi) {
        const bf16_t* xp = sT + ((kc * 4 + mi) * 64 + lane) * 8;
        bf16x8 xh = *(const bf16x8*)xp;
        bf16x8 xl = *(const bf16x8*)(xp + 16384);
        acc[mi] = MFMA32(cwh, xh, acc[mi]);
        acc[mi] = MFMA32(cwl, xh, acc[mi]);
        acc[mi] = MFMA32(cwh, xl, acc[mi]);
      }
      __builtin_amdgcn_s_setprio(0);
    }
    if ((u & 3) == 3) {
#pragma unroll
      for (int r = 0; r < 16; ++r) {
        float m = fmaxf(fmaxf(acc[0][r], acc[1][r]), fmaxf(acc[2][r], acc[3][r]));
        m = fmaxf(m, 0.f);  // relu folded into the max
#pragma unroll
        for (int off = 1; off < 32; off <<= 1) m = fmaxf(m, __shfl_xor(m, off));
        if (p31 == 0)
          gpart[(size_t)pb * 1024 + stc * 32 + 8 * (r >> 2) + 4 * hb + (r & 3)] = m;
      }
    }
  }
}

// ============ kgmax: g[c] = max over 512 rows of gpart[512][1024]
__global__ __launch_bounds__(256) void kgmax(const float* __restrict__ gpart, float* __restrict__ g) {
  int t = blockIdx.x * 256 + threadIdx.x;  // 8192 threads
  int c = t & 1023, rg = t >> 10;
  const float* gp = gpart + (size_t)rg * 64 * 1024 + c;
  float m = 0.f;
#pragma unroll 8
  for (int r = 0; r < 64; ++r) m = fmaxf(m, gp[(size_t)r * 1024]);
  atomicMax((unsigned int*)(g + c), __float_as_uint(m));  // all values >= 0
}

// ============ kc5 v3: c5[c] = W5[c][64:1088] @ g + b5[c], COALESCED.
__global__ __launch_bounds__(256) void kc5(
    const float* __restrict__ W5, const float* __restrict__ b5,
    const float* __restrict__ g, float* __restrict__ c5) {
  int lane = threadIdx.x & 63;
  int wv = blockIdx.x * 4 + (threadIdx.x >> 6);  // 128 waves
  float gv[16];
#pragma unroll
  for (int k = 0; k < 16; ++k) gv[k] = g[k * 64 + lane];
#pragma unroll
  for (int i = 0; i < 4; ++i) {
    int c = wv * 4 + i;  // 0..511
    const float* wrow = W5 + (size_t)c * 1088 + 64;
    float acc = 0.f;
#pragma unroll
    for (int k = 0; k < 16; ++k) acc = fmaf(wrow[k * 64 + lane], gv[k], acc);
#pragma unroll
    for (int off = 1; off < 64; off <<= 1) acc += __shfl_xor(acc, off);
    if (lane == 0) c5[c] = acc + b5[c];
  }
}

// ======================================================================
// mega2 v2 (R16 verbatim): h2 -> z5 -> z6 -> z7 -> out, 64-pt blocks.
// ======================================================================

__global__ __launch_bounds__(256, 2) void mega2(
    const bf16_t* __restrict__ h2gh, const bf16_t* __restrict__ h2gl,
    const bf16_t* __restrict__ W5h, const bf16_t* __restrict__ W5l, const float* __restrict__ c5,
    const bf16_t* __restrict__ W6h, const bf16_t* __restrict__ W6l, const float* __restrict__ b6,
    const bf16_t* __restrict__ W7h, const bf16_t* __restrict__ W7l, const float* __restrict__ b7,
    const float* __restrict__ w8, const float* __restrict__ b8v, float* __restrict__ out) {
  __shared__ __align__(16) bf16_t smem[32768];
  __shared__ float sp[4][64];
  int tid = threadIdx.x, lane = tid & 63;
  int w = __builtin_amdgcn_readfirstlane(tid >> 6);
  int hb = lane >> 5, p31 = lane & 31;
  int b = blockIdx.x;
  int B = b >> 1, half = b & 1;

  bf16x8 xh[4][2], xl[4][2];
#pragma unroll
  for (int kc = 0; kc < 4; ++kc)
#pragma unroll
    for (int mi = 0; mi < 2; ++mi) {
      size_t so = (((size_t)((B * 4 + kc) * 4 + half * 2 + mi)) * 64 + lane) * 8;
      xh[kc][mi] = *(const bf16x8*)(h2gh + so);
      xl[kc][mi] = *(const bf16x8*)(h2gl + so);
    }

  f32x16 z6a[2][2];
#pragma unroll
  for (int s = 0; s < 2; ++s)
#pragma unroll
    for (int r = 0; r < 16; ++r) {
      float bv = b6[(w * 2 + s) * 32 + 8 * (r >> 2) + 4 * hb + (r & 3)];
      z6a[s][0][r] = bv; z6a[s][1][r] = bv;
    }

  bf16x8 w5h[4], w5l[4];
  auto w5load = [&](int g) {
#pragma unroll
    for (int kc = 0; kc < 4; ++kc) {
      size_t wo = (((size_t)(g * 4 + w) * 4 + kc) * 64 + lane) * 8;
      w5h[kc] = *(const bf16x8*)(W5h + wo);
      w5l[kc] = *(const bf16x8*)(W5l + wo);
    }
  };
  w5load(0);

  bf16x8 cwh[2], cwl[2], nwh[2], nwl[2];
  auto w6load = [&](int g, int kc, bf16x8* hh, bf16x8* ll) {
#pragma unroll
    for (int s = 0; s < 2; ++s) {
      size_t wo = ((size_t)((w * 2 + s) * 32 + g * 8 + kc) * 64 + lane) * 8;
      hh[s] = *(const bf16x8*)(W6h + wo);
      ll[s] = *(const bf16x8*)(W6l + wo);
    }
  };

  for (int g5 = 0; g5 < 4; ++g5) {
    bf16_t* zbuf = smem + (g5 & 1) * 16384;
    int st5 = g5 * 4 + w;
    f32x16 a5[2];
    binit2(a5, c5, st5 * 32, hb);
    __builtin_amdgcn_s_setprio(1);
#pragma unroll
    for (int kc = 0; kc < 4; ++kc) {
#pragma unroll
      for (int mi = 0; mi < 2; ++mi) a5[mi] = MFMA32(w5h[kc], xh[kc][mi], a5[mi]);
#pragma unroll
      for (int mi = 0; mi < 2; ++mi) a5[mi] = MFMA32(w5l[kc], xh[kc][mi], a5[mi]);
#pragma unroll
      for (int mi = 0; mi < 2; ++mi) a5[mi] = MFMA32(w5h[kc], xl[kc][mi], a5[mi]);
    }
    __builtin_amdgcn_s_setprio(0);
    if (g5 < 3) w5load(g5 + 1);
#pragma unroll
    for (int mi = 0; mi < 2; ++mi) {
      Oct o = epi_pack(a5[mi], hb);
      epi_store_lds(o, zbuf, zbuf + 8192, ((w * 2 + hb) * 2 + mi) * 64, p31);
    }
    w6load(g5, 0, cwh, cwl);
    __syncthreads();
#pragma unroll
    for (int kc = 0; kc < 8; ++kc) {
      if (kc < 7) w6load(g5, kc + 1, nwh, nwl);
      bf16x8 zxh[2], zxl[2];
#pragma unroll
      for (int mi = 0; mi < 2; ++mi) {
        const bf16_t* xp = zbuf + ((kc * 2 + mi) * 64 + lane) * 8;
        zxh[mi] = *(const bf16x8*)xp;
        zxl[mi] = *(const bf16x8*)(xp + 8192);
      }
      __builtin_amdgcn_s_setprio(1);
#pragma unroll
      for (int s = 0; s < 2; ++s)
#pragma unroll
        for (int mi = 0; mi < 2; ++mi) z6a[s][mi] = MFMA32(cwh[s], zxh[mi], z6a[s][mi]);
#pragma unroll
      for (int s = 0; s < 2; ++s)
#pragma unroll
        for (int mi = 0; mi < 2; ++mi) z6a[s][mi] = MFMA32(cwl[s], zxh[mi], z6a[s][mi]);
#pragma unroll
      for (int s = 0; s < 2; ++s)
#pragma unroll
        for (int mi = 0; mi < 2; ++mi) z6a[s][mi] = MFMA32(cwh[s], zxl[mi], z6a[s][mi]);
      __builtin_amdgcn_s_setprio(0);
#pragma unroll
      for (int s = 0; s < 2; ++s) { cwh[s] = nwh[s]; cwl[s] = nwl[s]; }
    }
  }
  __syncthreads();
#pragma unroll
  for (int s = 0; s < 2; ++s) {
    int kcb = (w * 2 + s) * 2 + hb;
#pragma unroll
    for (int mi = 0; mi < 2; ++mi) {
      Oct o = epi_pack(z6a[s][mi], hb);
      epi_store_lds(o, smem, smem + 16384, (kcb * 2 + mi) * 64, p31);
    }
  }
  bf16x8 a7wh, a7wl, n7h, n7l;
  {
    size_t wo = ((size_t)(w * 16) * 64 + lane) * 8;
    a7wh = *(const bf16x8*)(W7h + wo);
    a7wl = *(const bf16x8*)(W7l + wo);
  }
  __syncthreads();
  f32x16 a7[2];
  binit2(a7, b7, w * 32, hb);
#pragma unroll
  for (int kc = 0; kc < 16; ++kc) {
    if (kc < 15) {
      size_t wo = ((size_t)(w * 16 + kc + 1) * 64 + lane) * 8;
      n7h = *(const bf16x8*)(W7h + wo);
      n7l = *(const bf16x8*)(W7l + wo);
    }
    bf16x8 zxh[2], zxl[2];
#pragma unroll
    for (int mi = 0; mi < 2; ++mi) {
      const bf16_t* xp = smem + ((kc * 2 + mi) * 64 + lane) * 8;
      zxh[mi] = *(const bf16x8*)xp;
      zxl[mi] = *(const bf16x8*)(xp + 16384);
    }
    __builtin_amdgcn_s_setprio(1);
#pragma unroll
    for (int mi = 0; mi < 2; ++mi) a7[mi] = MFMA32(a7wh, zxh[mi], a7[mi]);
#pragma unroll
    for (int mi = 0; mi < 2; ++mi) a7[mi] = MFMA32(a7wl, zxh[mi], a7[mi]);
#pragma unroll
    for (int mi = 0; mi < 2; ++mi) a7[mi] = MFMA32(a7wh, zxl[mi], a7[mi]);
    __builtin_amdgcn_s_setprio(0);
    a7wh = n7h; a7wl = n7l;
  }
  float w8v[16];
#pragma unroll
  for (int r = 0; r < 16; ++r) w8v[r] = w8[w * 32 + 8 * (r >> 2) + 4 * hb + (r & 3)];
#pragma unroll
  for (int mi = 0; mi < 2; ++mi) {
    float s = 0.f;
#pragma unroll
    for (int r = 0; r < 16; ++r) s = fmaf(relu(a7[mi][r]), w8v[r], s);
    s += __shfl_xor(s, 32);
    if (hb == 0) sp[w][mi * 32 + p31] = s;
  }
  __syncthreads();
  if (tid < 64)
    out[b * 64 + tid] = sp[0][tid] + sp[1][tid] + sp[2][tid] + sp[3][tid] + b8v[0];
}

extern "C" void kernel_launch(void* const* d_in, const int* in_sizes, int n_in,
                              void* d_out, int out_size, void* d_ws, size_t ws_size,
                              hipStream_t stream) {
  const float* x  = (const float*)d_in[0];
  const float* W1 = (const float*)d_in[1];  const float* b1 = (const float*)d_in[2];
  const float* W2 = (const float*)d_in[3];  const float* b2 = (const float*)d_in[4];
  const float* W3 = (const float*)d_in[5];  const float* b3 = (const float*)d_in[6];
  const float* W4 = (const float*)d_in[7];  const float* b4 = (const float*)d_in[8];
  const float* W5 = (const float*)d_in[9];  const float* b5 = (const float*)d_in[10];
  const float* W6 = (const float*)d_in[11]; const float* b6 = (const float*)d_in[12];
  const float* W7 = (const float*)d_in[13]; const float* b7 = (const float*)d_in[14];
  const float* W8 = (const float*)d_in[15]; const float* b8 = (const float*)d_in[16];
  float* out = (float*)d_out;

  // Workspace overlays:
  //   h2 pair [128,136)+[136,144)  L2->kl34max,mega2
  //   h1 pair [144,152)+[152,160)  kprep_k1a->L2
  //   gpart [208,210), g/c5 [210,..), weight frags after
  const size_t MB = 1ull << 20;
  char* ws = (char*)d_ws;
  bf16_t* h2h = (bf16_t*)(ws + 128 * MB);  bf16_t* h2l = (bf16_t*)(ws + 136 * MB);
  bf16_t* h1h = (bf16_t*)(ws + 144 * MB);  bf16_t* h1l = (bf16_t*)(ws + 152 * MB);
  float* gpart = (float*)(ws + 208 * MB);
  float* g     = (float*)(ws + 210 * MB);
  float* c5    = (float*)(ws + 210 * MB + 4096);
  char* wb = ws + 210 * MB + 65536;
  bf16_t* W2h = (bf16_t*)(wb);             bf16_t* W2l = (bf16_t*)(wb + 8192);
  bf16_t* W3h = (bf16_t*)(wb + 16384);     bf16_t* W3l = (bf16_t*)(wb + 32768);
  bf16_t* W4h = (bf16_t*)(wb + 49152);     bf16_t* W4l = (bf16_t*)(wb + 311296);
  bf16_t* W5h = (bf16_t*)(wb + 573440);    bf16_t* W5l = (bf16_t*)(wb + 638976);
  bf16_t* W6h = (bf16_t*)(wb + 704512);    bf16_t* W6l = (bf16_t*)(wb + 966656);
  bf16_t* W7h = (bf16_t*)(wb + 1228800);   bf16_t* W7l = (bf16_t*)(wb + 1294336);

  hipMemsetAsync(g, 0, 1024 * sizeof(float), stream);  // max identity (relu outputs >= 0)

  PrepAll pa;
  pa.seg[0] = {W2, W2h, W2l, 64, 64, 2};
  pa.seg[1] = {W3, W3h, W3l, 64, 64, 4};
  pa.seg[2] = {W4, W4h, W4l, 128, 128, 64};
  pa.seg[3] = {W5, W5h, W5l, 1088, 64, 16};   // W5[:, :64]
  pa.seg[4] = {W6, W6h, W6l, 512, 512, 64};
  pa.seg[5] = {W7, W7h, W7l, 256, 256, 16};

  kprep_k1a<<<422, 256, 0, stream>>>(pa, x, W1, b1, h1h, h1l);                // prep + L1 fused
  gemmS<2, 64, 0><<<dim3(256, 1), 256, 0, stream>>>(
      h1h, h1l, W2h, W2l, b2, 4, h2h, h2l, nullptr, nullptr, nullptr);        // L2
  kl34max<<<256, 512, 0, stream>>>(h2h, h2l, W3h, W3l, b3, W4h, W4l, b4, gpart);  // L3+L4+max
  kgmax<<<32, 256, 0, stream>>>(gpart, g);
  kc5<<<32, 256, 0, stream>>>(W5, b5, g, c5);
  mega2<<<1024, 256, 0, stream>>>(h2h, h2l, W5h, W5l, c5, W6h, W6l, b6,
                                  W7h, W7l, b7, W8, b8, out);                 // L5..L8 fused
}

// Round 18
// 243.725 us; speedup vs baseline: 1.1309x; 1.0070x over previous
//
#include <hip/hip_runtime.h>

#define NPTS 65536

typedef __bf16 bf16_t;
typedef __bf16 bf16x8 __attribute__((ext_vector_type(8)));
typedef float f32x16 __attribute__((ext_vector_type(16)));

#define MFMA32(A, B, C) __builtin_amdgcn_mfma_f32_32x32x16_bf16(A, B, C, 0, 0, 0)

__device__ __forceinline__ float relu(float v) { return v > 0.f ? v : 0.f; }

// ======================================================================
// Layouts (128-pt blocks, 4 mi slots):
// Activation (C ch): octet idx = ((b*(C/16)+kc)*4+mi)*64 + l
//   point = b*128 + mi*32 + (l&31); channel = kc*16 + (l>>5)*8 + j
// Weight (N x K): octet idx = (st*(K/16)+kc)*64 + l; n = st*32+(l&31); k = kc*16+(l>>5)*8+j
// ======================================================================

struct PrepSeg { const float* src; bf16_t* h; bf16_t* l; int SW; int K; int nblk; };
struct PrepAll { PrepSeg seg[6]; };

// ============ kprep_k1a: FUSED independent front-end work (one dispatch).
// Blocks [0,166): weight split/pack. Blocks [166,422): h1 = relu(x@W1.T+b1).
__global__ __launch_bounds__(256, 2) void kprep_k1a(
    PrepAll pa,
    const float* __restrict__ x, const float* __restrict__ W1, const float* __restrict__ b1,
    bf16_t* __restrict__ h1h, bf16_t* __restrict__ h1l) {
  if (blockIdx.x < 166) {
    int blk = blockIdx.x, i = 0;
    while (blk >= pa.seg[i].nblk) { blk -= pa.seg[i].nblk; ++i; }
    const PrepSeg sg = pa.seg[i];
    int t8 = blk * 256 + threadIdx.x;
    int l = t8 & 63;
    int rest = t8 >> 6;
    int NKC = sg.K >> 4;
    int kc = rest % NKC, st = rest / NKC;
    int n = st * 32 + (l & 31);
    int k0 = kc * 16 + (l >> 5) * 8;
    const float* src = sg.src + (size_t)n * sg.SW + k0;
    bf16x8 hv, lv;
#pragma unroll
    for (int j = 0; j < 8; ++j) {
      float v = src[j];
      bf16_t h = (bf16_t)v;
      hv[j] = h; lv[j] = (bf16_t)(v - (float)h);
    }
    *(bf16x8*)(sg.h + (size_t)t8 * 8) = hv;
    *(bf16x8*)(sg.l + (size_t)t8 * 8) = lv;
  } else {
    int p = (blockIdx.x - 166) * 256 + threadIdx.x;
    float x0 = x[p * 3 + 0], x1 = x[p * 3 + 1], x2 = x[p * 3 + 2];
    int b = p >> 7, mi = (p >> 5) & 3, p31 = p & 31;
#pragma unroll
    for (int kc = 0; kc < 4; ++kc)
#pragma unroll
      for (int hbw = 0; hbw < 2; ++hbw) {
        bf16x8 hv, lv;
#pragma unroll
        for (int j = 0; j < 8; ++j) {
          int c = kc * 16 + hbw * 8 + j;
          float v = relu(fmaf(W1[c * 3], x0, fmaf(W1[c * 3 + 1], x1, fmaf(W1[c * 3 + 2], x2, b1[c]))));
          bf16_t h = (bf16_t)v;
          hv[j] = h; lv[j] = (bf16_t)(v - (float)h);
        }
        size_t off = (((size_t)(b * 4 + kc) * 4 + mi) * 64 + hbw * 32 + p31) * 8;
        *(bf16x8*)(h1h + off) = hv;
        *(bf16x8*)(h1l + off) = lv;
      }
  }
}

// ============ shared epilogue helpers
struct Oct { bf16x8 h0, l0, h1, l1; };
__device__ __forceinline__ Oct epi_pack(const f32x16& accv, int hb) {
  float a[16], rcv[8];
#pragma unroll
  for (int r = 0; r < 16; ++r) a[r] = relu(accv[r]);
#pragma unroll
  for (int j = 0; j < 8; ++j) rcv[j] = __shfl_xor(hb ? a[j] : a[8 + j], 32);
  float o0[8], o1[8];
#pragma unroll
  for (int j = 0; j < 4; ++j) {
    o0[j]     = hb ? rcv[j]     : a[j];
    o0[4 + j] = hb ? a[8 + j]   : rcv[j];
    o1[j]     = hb ? rcv[4 + j] : a[4 + j];
    o1[4 + j] = hb ? a[12 + j]  : rcv[4 + j];
  }
  Oct o;
#pragma unroll
  for (int j = 0; j < 8; ++j) {
    bf16_t x0 = (bf16_t)o0[j]; o.h0[j] = x0; o.l0[j] = (bf16_t)(o0[j] - (float)x0);
    bf16_t x1 = (bf16_t)o1[j]; o.h1[j] = x1; o.l1[j] = (bf16_t)(o1[j] - (float)x1);
  }
  return o;
}

__device__ __forceinline__ void epi_store_lds(const Oct& o, bf16_t* H, bf16_t* L, int ob, int p31) {
  *(bf16x8*)(H + (ob + p31) * 8)      = o.h0;
  *(bf16x8*)(H + (ob + 32 + p31) * 8) = o.h1;
  *(bf16x8*)(L + (ob + p31) * 8)      = o.l0;
  *(bf16x8*)(L + (ob + 32 + p31) * 8) = o.l1;
}

__device__ __forceinline__ void binit2(f32x16 acc[2], const float* bias, int base, int hb) {
#pragma unroll
  for (int r = 0; r < 16; ++r) {
    float bv = bias[base + 8 * (r >> 2) + 4 * hb + (r & 3)];
    acc[0][r] = bv; acc[1][r] = bv;
  }
}

// ============ gemmS: D = W·X^T, 3-term split 32x32x16 bf16 MFMA (L2 only)
template <int PB, int K, int MODE>
__global__ __launch_bounds__(256, 3) void gemmS(
    const bf16_t* __restrict__ Ah, const bf16_t* __restrict__ Al,
    const bf16_t* __restrict__ Wh, const bf16_t* __restrict__ Wl,
    const float* __restrict__ bias, int nko,
    bf16_t* __restrict__ Oh, bf16_t* __restrict__ Ol,
    float* __restrict__ aux, const float* __restrict__ w8, const float* __restrict__ b8) {
  constexpr int WC = 4 / PB;
  constexpr int NKC = K / 16;
  constexpr int KG = 2;
  constexpr int NG = NKC / KG;
  __shared__ bf16_t smem[2][PB][2][KG * 2048];

  int tid = threadIdx.x;
  int lane = tid & 63;
  int w = __builtin_amdgcn_readfirstlane(tid >> 6);
  int rg = w / WC, cw = w % WC;
  int hb = lane >> 5, p31 = lane & 31;
  int bx = blockIdx.x;
  int st0 = blockIdx.y * WC + cw;
  int bblk = bx * PB + rg;

  f32x16 acc[4];
#pragma unroll
  for (int r = 0; r < 16; ++r) {
    float bv = bias[st0 * 32 + 8 * (r >> 2) + 4 * hb + (r & 3)];
#pragma unroll
    for (int mi = 0; mi < 4; ++mi) acc[mi][r] = bv;
  }

  auto stage = [&](int buf, int g) {
#pragma unroll
    for (int i = 0; i < PB * 4; ++i) {
      int u = i * 256 + tid;
      int rgs = u >> 10, rem = u & 1023;
      int t = rem >> 9, inner = rem & 511;
      const bf16_t* src = (t ? Al : Ah) +
          ((size_t)(bx * PB + rgs) * NKC + g * KG) * 2048 + inner * 8;
      *(bf16x8*)&smem[buf][rgs][t][inner * 8] = *(const bf16x8*)src;
    }
  };

  bf16x8 wch[KG], wcl[KG], wnh[KG], wnl[KG];
  auto wload = [&](int g, bf16x8* h, bf16x8* l) {
#pragma unroll
    for (int kcl = 0; kcl < KG; ++kcl) {
      size_t wo = (((size_t)st0 * NKC + g * KG + kcl) * 64 + lane) * 8;
      h[kcl] = *(const bf16x8*)(Wh + wo);
      l[kcl] = *(const bf16x8*)(Wl + wo);
    }
  };

  auto compute = [&](int buf, bf16x8* h, bf16x8* l) {
#pragma unroll
    for (int kcl = 0; kcl < KG; ++kcl)
#pragma unroll
      for (int mi = 0; mi < 4; ++mi) {
        const bf16_t* xp = &smem[buf][rg][0][((kcl * 4 + mi) * 64 + lane) * 8];
        bf16x8 xh = *(const bf16x8*)xp;
        bf16x8 xl = *(const bf16x8*)(xp + KG * 2048);
        acc[mi] = MFMA32(h[kcl], xh, acc[mi]);
        acc[mi] = MFMA32(l[kcl], xh, acc[mi]);
        acc[mi] = MFMA32(h[kcl], xl, acc[mi]);
      }
  };

  stage(0, 0);
  wload(0, wch, wcl);
  for (int g = 0; g < NG; ++g) {
    __syncthreads();
    if (g + 1 < NG) {
      stage((g + 1) & 1, g + 1);
      wload(g + 1, wnh, wnl);
    }
    compute(g & 1, wch, wcl);
#pragma unroll
    for (int kcl = 0; kcl < KG; ++kcl) { wch[kcl] = wnh[kcl]; wcl[kcl] = wnl[kcl]; }
  }

  if constexpr (MODE == 0) {
#pragma unroll
    for (int mi = 0; mi < 4; ++mi) {
      Oct o = epi_pack(acc[mi], hb);
      int kco = st0 * 2 + hb;
      size_t ob = ((size_t)(bblk * nko + kco) * 4 + mi) * 64;
      *(bf16x8*)(Oh + (ob + p31) * 8)      = o.h0;
      *(bf16x8*)(Ol + (ob + p31) * 8)      = o.l0;
      *(bf16x8*)(Oh + (ob + 32 + p31) * 8) = o.h1;
      *(bf16x8*)(Ol + (ob + 32 + p31) * 8) = o.l1;
    }
  } else if constexpr (MODE == 1) {
#pragma unroll
    for (int r = 0; r < 16; ++r) {
      float m = relu(acc[0][r]);
#pragma unroll
      for (int mi = 1; mi < 4; ++mi) m = fmaxf(m, relu(acc[mi][r]));
#pragma unroll
      for (int off = 1; off < 32; off <<= 1) m = fmaxf(m, __shfl_xor(m, off));
      if (p31 == 0)
        aux[(size_t)bx * 1024 + st0 * 32 + 8 * (r >> 2) + 4 * hb + (r & 3)] = m;
    }
  } else {
    __shared__ float sp[4][128];
    float w8v[16];
#pragma unroll
    for (int r = 0; r < 16; ++r) w8v[r] = w8[st0 * 32 + 8 * (r >> 2) + 4 * hb + (r & 3)];
#pragma unroll
    for (int mi = 0; mi < 4; ++mi) {
      float s = 0.f;
#pragma unroll
      for (int r = 0; r < 16; ++r) s = fmaf(relu(acc[mi][r]), w8v[r], s);
      s += __shfl_xor(s, 32);
      if (hb == 0) sp[w][mi * 32 + p31] = s;
    }
    __syncthreads();
    if (tid < 128)
      aux[(size_t)bx * 128 + tid] = sp[0][tid] + sp[1][tid] + sp[2][tid] + sp[3][tid] + b8[0];
  }
}

// ============ kl34max v7 (R17 verbatim, measured 76.6 us): FUSED L3+L4,
// 2 tiles/block, 32 double-kc phases with block-coop weight staging.
__global__ __launch_bounds__(512, 1) void kl34max(
    const bf16_t* __restrict__ h2h, const bf16_t* __restrict__ h2l,
    const bf16_t* __restrict__ W3h, const bf16_t* __restrict__ W3l,
    const float* __restrict__ b3,
    const bf16_t* __restrict__ Wh, const bf16_t* __restrict__ Wl,
    const float* __restrict__ bias, float* __restrict__ gpart) {
  __shared__ __align__(16) bf16_t sA[81920];  // y3 [0,65536); wq [65536,81920)
  bf16_t* wq = sA + 65536;
  int tid = threadIdx.x, lane = tid & 63;
  int w = __builtin_amdgcn_readfirstlane(tid >> 6);   // 0..7
  int w3 = w & 3, t = w >> 2;                         // strip-slot, tile
  int hb = lane >> 5, p31 = lane & 31;
  int bx = blockIdx.x;
  int pb = bx * 2 + t;
  int rot = (bx >> 2) & 7;
  bf16_t* sT = sA + t * 32768;

  // block-coop staging of one double-kc phase (16 KB; 2 wave-DMAs per wave)
  auto issueW = [&](int u) {
    int jj = u >> 2, kp = (u & 3) * 2;
#pragma unroll
    for (int i = 0; i < 2; ++i) {
      int unit = i * 8 + w;                 // 0..15, wave-uniform
      int sslot = unit & 3;                 // strip-slot staged
      int q     = (unit >> 2) & 1;          // kc within pair
      int part  = unit >> 3;                // 0=h, 1=l
      int st = ((jj + rot) & 7) * 4 + sslot;
      int kc = kp + q;
      const bf16_t* W = part ? Wl : Wh;
      const bf16_t* gp = W + ((size_t)(st * 8 + kc) * 64 + lane) * 8;
      bf16_t* lp = wq + (u & 1) * 8192 + (sslot * 4 + q * 2 + part) * 512;
      __builtin_amdgcn_global_load_lds(
          (const __attribute__((address_space(1))) void*)gp,
          (__attribute__((address_space(3))) void*)lp, 16, 0, 0);
    }
  };
  issueW(0);  // latency hides under all of phase 1

  // ---- phase 1: y3(tile t) = relu(h2@W3.T+b3) -> LDS. h2 B-frags for mi=w3.
  {
    bf16x8 hx[4], lx[4];
#pragma unroll
    for (int kc = 0; kc < 4; ++kc) {
      size_t so = (((size_t)(pb * 4 + kc) * 4 + w3) * 64 + lane) * 8;
      hx[kc] = *(const bf16x8*)(h2h + so);
      lx[kc] = *(const bf16x8*)(h2l + so);
    }
#pragma unroll
    for (int spr = 0; spr < 2; ++spr) {
      f32x16 a3[2];
#pragma unroll
      for (int s = 0; s < 2; ++s) {
        int st = spr * 2 + s;
#pragma unroll
        for (int r = 0; r < 16; ++r)
          a3[s][r] = b3[st * 32 + 8 * (r >> 2) + 4 * hb + (r & 3)];
      }
#pragma unroll
      for (int kc = 0; kc < 4; ++kc)
#pragma unroll
        for (int s = 0; s < 2; ++s) {
          int st = spr * 2 + s;
          size_t wo = ((size_t)(st * 4 + kc) * 64 + lane) * 8;
          bf16x8 wh3 = *(const bf16x8*)(W3h + wo);
          bf16x8 wl3 = *(const bf16x8*)(W3l + wo);
          a3[s] = MFMA32(wh3, hx[kc], a3[s]);
          a3[s] = MFMA32(wl3, hx[kc], a3[s]);
          a3[s] = MFMA32(wh3, lx[kc], a3[s]);
        }
#pragma unroll
      for (int s = 0; s < 2; ++s) {
        int st = spr * 2 + s;
        Oct o = epi_pack(a3[s], hb);
        epi_store_lds(o, sT, sT + 16384, ((st * 2 + hb) * 4 + w3) * 64, p31);
      }
    }
  }
  __syncthreads();  // y3 ready

  // ---- phase 2: 32 double-kc phases
  f32x16 acc[4];
#pragma unroll 1
  for (int u = 0; u < 32; ++u) {
    asm volatile("s_waitcnt vmcnt(0)" ::: "memory");  // my phase-u DMAs (+ older stores) done
    __builtin_amdgcn_sched_barrier(0);
    __builtin_amdgcn_s_barrier();                     // all waves' phase-u weights visible
    if (u + 1 < 32) issueW(u + 1);                    // post-barrier: recycled slot is dead
    int jj = u >> 2, kp = (u & 3) * 2;
    int stc = ((jj + rot) & 7) * 4 + w3;
    if ((u & 3) == 0) {
#pragma unroll
      for (int r = 0; r < 16; ++r) {
        float bv = bias[stc * 32 + 8 * (r >> 2) + 4 * hb + (r & 3)];
#pragma unroll
        for (int mi = 0; mi < 4; ++mi) acc[mi][r] = bv;
      }
    }
    const bf16_t* wb = wq + (u & 1) * 8192;
#pragma unroll
    for (int q = 0; q < 2; ++q) {
      int kc = kp + q;
      bf16x8 cwh = *(const bf16x8*)(wb + (w3 * 4 + q * 2) * 512 + lane * 8);
      bf16x8 cwl = *(const bf16x8*)(wb + (w3 * 4 + q * 2 + 1) * 512 + lane * 8);
      __builtin_amdgcn_s_setprio(1);
#pragma unroll
      for (int mi = 0; mi < 4; ++mi) {
        const bf16_t* xp = sT + ((kc * 4 + mi) * 64 + lane) * 8;
        bf16x8 xh = *(const bf16x8*)xp;
        bf16x8 xl = *(const bf16x8*)(xp + 16384);
        acc[mi] = MFMA32(cwh, xh, acc[mi]);
        acc[mi] = MFMA32(cwl, xh, acc[mi]);
        acc[mi] = MFMA32(cwh, xl, acc[mi]);
      }
      __builtin_amdgcn_s_setprio(0);
    }
    if ((u & 3) == 3) {
#pragma unroll
      for (int r = 0; r < 16; ++r) {
        float m = fmaxf(fmaxf(acc[0][r], acc[1][r]), fmaxf(acc[2][r], acc[3][r]));
        m = fmaxf(m, 0.f);  // relu folded into the max
#pragma unroll
        for (int off = 1; off < 32; off <<= 1) m = fmaxf(m, __shfl_xor(m, off));
        if (p31 == 0)
          gpart[(size_t)pb * 1024 + stc * 32 + 8 * (r >> 2) + 4 * hb + (r & 3)] = m;
      }
    }
  }
}

// ============ kgmax: g[c] = max over 512 rows of gpart[512][1024]
__global__ __launch_bounds__(256) void kgmax(const float* __restrict__ gpart, float* __restrict__ g) {
  int t = blockIdx.x * 256 + threadIdx.x;  // 8192 threads
  int c = t & 1023, rg = t >> 10;
  const float* gp = gpart + (size_t)rg * 64 * 1024 + c;
  float m = 0.f;
#pragma unroll 8
  for (int r = 0; r < 64; ++r) m = fmaxf(m, gp[(size_t)r * 1024]);
  atomicMax((unsigned int*)(g + c), __float_as_uint(m));  // all values >= 0
}

// ============ kc5 v3: c5[c] = W5[c][64:1088] @ g + b5[c], COALESCED.
__global__ __launch_bounds__(256) void kc5(
    const float* __restrict__ W5, const float* __restrict__ b5,
    const float* __restrict__ g, float* __restrict__ c5) {
  int lane = threadIdx.x & 63;
  int wv = blockIdx.x * 4 + (threadIdx.x >> 6);  // 128 waves
  float gv[16];
#pragma unroll
  for (int k = 0; k < 16; ++k) gv[k] = g[k * 64 + lane];
#pragma unroll
  for (int i = 0; i < 4; ++i) {
    int c = wv * 4 + i;  // 0..511
    const float* wrow = W5 + (size_t)c * 1088 + 64;
    float acc = 0.f;
#pragma unroll
    for (int k = 0; k < 16; ++k) acc = fmaf(wrow[k * 64 + lane], gv[k], acc);
#pragma unroll
    for (int off = 1; off < 64; off <<= 1) acc += __shfl_xor(acc, off);
    if (lane == 0) c5[c] = acc + b5[c];
  }
}

// ======================================================================
// mega2 v3: h2 -> z5 -> z6 -> z7 -> out, 64-pt blocks. Changes vs v2 (R17):
// L6 and L7 weight pipelines deepened 1 -> 2 (3-slot rotating register
// buffers, all indices compile-time inside unrolled loops) to cover the
// 200-300 cyc L2 latency that the 1-deep pipeline (~192 cyc cover) exposed.
// Sync structure, MFMA order, and operands bit-identical.
// ======================================================================

__global__ __launch_bounds__(256, 2) void mega2(
    const bf16_t* __restrict__ h2gh, const bf16_t* __restrict__ h2gl,
    const bf16_t* __restrict__ W5h, const bf16_t* __restrict__ W5l, const float* __restrict__ c5,
    const bf16_t* __restrict__ W6h, const bf16_t* __restrict__ W6l, const float* __restrict__ b6,
    const bf16_t* __restrict__ W7h, const bf16_t* __restrict__ W7l, const float* __restrict__ b7,
    const float* __restrict__ w8, const float* __restrict__ b8v, float* __restrict__ out) {
  __shared__ __align__(16) bf16_t smem[32768];
  __shared__ float sp[4][64];
  int tid = threadIdx.x, lane = tid & 63;
  int w = __builtin_amdgcn_readfirstlane(tid >> 6);
  int hb = lane >> 5, p31 = lane & 31;
  int b = blockIdx.x;
  int B = b >> 1, half = b & 1;

  bf16x8 xh[4][2], xl[4][2];
#pragma unroll
  for (int kc = 0; kc < 4; ++kc)
#pragma unroll
    for (int mi = 0; mi < 2; ++mi) {
      size_t so = (((size_t)((B * 4 + kc) * 4 + half * 2 + mi)) * 64 + lane) * 8;
      xh[kc][mi] = *(const bf16x8*)(h2gh + so);
      xl[kc][mi] = *(const bf16x8*)(h2gl + so);
    }

  f32x16 z6a[2][2];
#pragma unroll
  for (int s = 0; s < 2; ++s)
#pragma unroll
    for (int r = 0; r < 16; ++r) {
      float bv = b6[(w * 2 + s) * 32 + 8 * (r >> 2) + 4 * hb + (r & 3)];
      z6a[s][0][r] = bv; z6a[s][1][r] = bv;
    }

  bf16x8 w5h[4], w5l[4];
  auto w5load = [&](int g) {
#pragma unroll
    for (int kc = 0; kc < 4; ++kc) {
      size_t wo = (((size_t)(g * 4 + w) * 4 + kc) * 64 + lane) * 8;
      w5h[kc] = *(const bf16x8*)(W5h + wo);
      w5l[kc] = *(const bf16x8*)(W5l + wo);
    }
  };
  w5load(0);

  // 2-deep W6 pipeline: 3-slot rotating buffer [slot][s][h/l]
  bf16x8 w6p[3][2][2];
  auto w6loadp = [&](int g, int kc, int slot) {
#pragma unroll
    for (int s = 0; s < 2; ++s) {
      size_t wo = ((size_t)((w * 2 + s) * 32 + g * 8 + kc) * 64 + lane) * 8;
      w6p[slot][s][0] = *(const bf16x8*)(W6h + wo);
      w6p[slot][s][1] = *(const bf16x8*)(W6l + wo);
    }
  };

  for (int g5 = 0; g5 < 4; ++g5) {
    bf16_t* zbuf = smem + (g5 & 1) * 16384;
    int st5 = g5 * 4 + w;
    f32x16 a5[2];
    binit2(a5, c5, st5 * 32, hb);
    __builtin_amdgcn_s_setprio(1);
#pragma unroll
    for (int kc = 0; kc < 4; ++kc) {
#pragma unroll
      for (int mi = 0; mi < 2; ++mi) a5[mi] = MFMA32(w5h[kc], xh[kc][mi], a5[mi]);
#pragma unroll
      for (int mi = 0; mi < 2; ++mi) a5[mi] = MFMA32(w5l[kc], xh[kc][mi], a5[mi]);
#pragma unroll
      for (int mi = 0; mi < 2; ++mi) a5[mi] = MFMA32(w5h[kc], xl[kc][mi], a5[mi]);
    }
    __builtin_amdgcn_s_setprio(0);
    if (g5 < 3) w5load(g5 + 1);
#pragma unroll
    for (int mi = 0; mi < 2; ++mi) {
      Oct o = epi_pack(a5[mi], hb);
      epi_store_lds(o, zbuf, zbuf + 8192, ((w * 2 + hb) * 2 + mi) * 64, p31);
    }
    w6loadp(g5, 0, 0);  // issue kc=0,1 before barrier: latency hides under it
    w6loadp(g5, 1, 1);
    __syncthreads();
#pragma unroll
    for (int kc = 0; kc < 8; ++kc) {
      if (kc + 2 < 8) w6loadp(g5, kc + 2, (kc + 2) % 3);
      bf16x8 zxh[2], zxl[2];
#pragma unroll
      for (int mi = 0; mi < 2; ++mi) {
        const bf16_t* xp = zbuf + ((kc * 2 + mi) * 64 + lane) * 8;
        zxh[mi] = *(const bf16x8*)xp;
        zxl[mi] = *(const bf16x8*)(xp + 8192);
      }
      __builtin_amdgcn_s_setprio(1);
#pragma unroll
      for (int s = 0; s < 2; ++s)
#pragma unroll
        for (int mi = 0; mi < 2; ++mi) z6a[s][mi] = MFMA32(w6p[kc % 3][s][0], zxh[mi], z6a[s][mi]);
#pragma unroll
      for (int s = 0; s < 2; ++s)
#pragma unroll
        for (int mi = 0; mi < 2; ++mi) z6a[s][mi] = MFMA32(w6p[kc % 3][s][1], zxh[mi], z6a[s][mi]);
#pragma unroll
      for (int s = 0; s < 2; ++s)
#pragma unroll
        for (int mi = 0; mi < 2; ++mi) z6a[s][mi] = MFMA32(w6p[kc % 3][s][0], zxl[mi], z6a[s][mi]);
      __builtin_amdgcn_s_setprio(0);
    }
  }
  __syncthreads();
#pragma unroll
  for (int s = 0; s < 2; ++s) {
    int kcb = (w * 2 + s) * 2 + hb;
#pragma unroll
    for (int mi = 0; mi < 2; ++mi) {
      Oct o = epi_pack(z6a[s][mi], hb);
      epi_store_lds(o, smem, smem + 16384, (kcb * 2 + mi) * 64, p31);
    }
  }
  // 2-deep W7 pipeline: 3-slot rotating buffer [slot][h/l]; kc=0,1 under barrier
  bf16x8 w7p[3][2];
  auto w7loadp = [&](int kc, int slot) {
    size_t wo = ((size_t)(w * 16 + kc) * 64 + lane) * 8;
    w7p[slot][0] = *(const bf16x8*)(W7h + wo);
    w7p[slot][1] = *(const bf16x8*)(W7l + wo);
  };
  w7loadp(0, 0);
  w7loadp(1, 1);
  __syncthreads();
  f32x16 a7[2];
  binit2(a7, b7, w * 32, hb);
#pragma unroll
  for (int kc = 0; kc < 16; ++kc) {
    if (kc + 2 < 16) w7loadp(kc + 2, (kc + 2) % 3);
    bf16x8 zxh[2], zxl[2];
#pragma unroll
    for (int mi = 0; mi < 2; ++mi) {
      const bf16_t* xp = smem + ((kc * 2 + mi) * 64 + lane) * 8;
      zxh[mi] = *(const bf16x8*)xp;
      zxl[mi] = *(const bf16x8*)(xp + 16384);
    }
    __builtin_amdgcn_s_setprio(1);
#pragma unroll
    for (int mi = 0; mi < 2; ++mi) a7[mi] = MFMA32(w7p[kc % 3][0], zxh[mi], a7[mi]);
#pragma unroll
    for (int mi = 0; mi < 2; ++mi) a7[mi] = MFMA32(w7p[kc % 3][1], zxh[mi], a7[mi]);
#pragma unroll
    for (int mi = 0; mi < 2; ++mi) a7[mi] = MFMA32(w7p[kc % 3][0], zxl[mi], a7[mi]);
    __builtin_amdgcn_s_setprio(0);
  }
  float w8v[16];
#pragma unroll
  for (int r = 0; r < 16; ++r) w8v[r] = w8[w * 32 + 8 * (r >> 2) + 4 * hb + (r & 3)];
#pragma unroll
  for (int mi = 0; mi < 2; ++mi) {
    float s = 0.f;
#pragma unroll
    for (int r = 0; r < 16; ++r) s = fmaf(relu(a7[mi][r]), w8v[r], s);
    s += __shfl_xor(s, 32);
    if (hb == 0) sp[w][mi * 32 + p31] = s;
  }
  __syncthreads();
  if (tid < 64)
    out[b * 64 + tid] = sp[0][tid] + sp[1][tid] + sp[2][tid] + sp[3][tid] + b8v[0];
}

extern "C" void kernel_launch(void* const* d_in, const int* in_sizes, int n_in,
                              void* d_out, int out_size, void* d_ws, size_t ws_size,
                              hipStream_t stream) {
  const float* x  = (const float*)d_in[0];
  const float* W1 = (const float*)d_in[1];  const float* b1 = (const float*)d_in[2];
  const float* W2 = (const float*)d_in[3];  const float* b2 = (const float*)d_in[4];
  const float* W3 = (const float*)d_in[5];  const float* b3 = (const float*)d_in[6];
  const float* W4 = (const float*)d_in[7];  const float* b4 = (const float*)d_in[8];
  const float* W5 = (const float*)d_in[9];  const float* b5 = (const float*)d_in[10];
  const float* W6 = (const float*)d_in[11]; const float* b6 = (const float*)d_in[12];
  const float* W7 = (const float*)d_in[13]; const float* b7 = (const float*)d_in[14];
  const float* W8 = (const float*)d_in[15]; const float* b8 = (const float*)d_in[16];
  float* out = (float*)d_out;

  // Workspace overlays:
  //   h2 pair [128,136)+[136,144)  L2->kl34max,mega2
  //   h1 pair [144,152)+[152,160)  kprep_k1a->L2
  //   gpart [208,210), g/c5 [210,..), weight frags after
  const size_t MB = 1ull << 20;
  char* ws = (char*)d_ws;
  bf16_t* h2h = (bf16_t*)(ws + 128 * MB);  bf16_t* h2l = (bf16_t*)(ws + 136 * MB);
  bf16_t* h1h = (bf16_t*)(ws + 144 * MB);  bf16_t* h1l = (bf16_t*)(ws + 152 * MB);
  float* gpart = (float*)(ws + 208 * MB);
  float* g     = (float*)(ws + 210 * MB);
  float* c5    = (float*)(ws + 210 * MB + 4096);
  char* wb = ws + 210 * MB + 65536;
  bf16_t* W2h = (bf16_t*)(wb);             bf16_t* W2l = (bf16_t*)(wb + 8192);
  bf16_t* W3h = (bf16_t*)(wb + 16384);     bf16_t* W3l = (bf16_t*)(wb + 32768);
  bf16_t* W4h = (bf16_t*)(wb + 49152);     bf16_t* W4l = (bf16_t*)(wb + 311296);
  bf16_t* W5h = (bf16_t*)(wb + 573440);    bf16_t* W5l = (bf16_t*)(wb + 638976);
  bf16_t* W6h = (bf16_t*)(wb + 704512);    bf16_t* W6l = (bf16_t*)(wb + 966656);
  bf16_t* W7h = (bf16_t*)(wb + 1228800);   bf16_t* W7l = (bf16_t*)(wb + 1294336);

  hipMemsetAsync(g, 0, 1024 * sizeof(float), stream);  // max identity (relu outputs >= 0)

  PrepAll pa;
  pa.seg[0] = {W2, W2h, W2l, 64, 64, 2};
  pa.seg[1] = {W3, W3h, W3l, 64, 64, 4};
  pa.seg[2] = {W4, W4h, W4l, 128, 128, 64};
  pa.seg[3] = {W5, W5h, W5l, 1088, 64, 16};   // W5[:, :64]
  pa.seg[4] = {W6, W6h, W6l, 512, 512, 64};
  pa.seg[5] = {W7, W7h, W7l, 256, 256, 16};

  kprep_k1a<<<422, 256, 0, stream>>>(pa, x, W1, b1, h1h, h1l);                // prep + L1 fused
  gemmS<2, 64, 0><<<dim3(256, 1), 256, 0, stream>>>(
      h1h, h1l, W2h, W2l, b2, 4, h2h, h2l, nullptr, nullptr, nullptr);        // L2
  kl34max<<<256, 512, 0, stream>>>(h2h, h2l, W3h, W3l, b3, W4h, W4l, b4, gpart);  // L3+L4+max
  kgmax<<<32, 256, 0, stream>>>(gpart, g);
  kc5<<<32, 256, 0, stream>>>(W5, b5, g, c5);
  mega2<<<1024, 256, 0, stream>>>(h2h, h2l, W5h, W5l, c5, W6h, W6l, b6,
                                  W7h, W7l, b7, W8, b8, out);                 // L5..L8 fused
}